// Round 21
// baseline (344.346 us; speedup 1.0000x reference)
//
#include <hip/hip_runtime.h>

typedef unsigned short u16;
typedef unsigned int   u32;
typedef u16   u16x4 __attribute__((ext_vector_type(4)));
typedef u16   u16x8 __attribute__((ext_vector_type(8)));
typedef short s16x8 __attribute__((ext_vector_type(8)));
typedef u32   u32x4 __attribute__((ext_vector_type(4)));
typedef float f32x4 __attribute__((ext_vector_type(4)));
typedef _Float16 f16x8 __attribute__((ext_vector_type(8)));

__device__ __forceinline__ u16 f2b(float f) {
  u32 u = __builtin_bit_cast(u32, f);
  u32 r = (u + 0x7fffu + ((u >> 16) & 1u)) >> 16;
  return (u16)r;
}
__device__ __forceinline__ float b2f(u16 h) {
  return __builtin_bit_cast(float, (u32)h << 16);
}
__device__ __forceinline__ u16 f2h(float f) {
  _Float16 h = (_Float16)f;           // v_cvt_f16_f32 (RNE)
  return __builtin_bit_cast(u16, h);
}
__device__ __forceinline__ u32 cvtpk(float a, float b) {  // low16=bf16(a), high16=bf16(b)
  u32 r; asm("v_cvt_pk_bf16_f32 %0, %1, %2" : "=v"(r) : "v"(a), "v"(b)); return r;
}

__device__ __forceinline__ void async16(void* l, const void* g) {
  __builtin_amdgcn_global_load_lds((const __attribute__((address_space(1))) u32*)g,
                                   (__attribute__((address_space(3))) u32*)l, 16, 0, 0);
}

__device__ __forceinline__ float wave_sum(float v) {
#pragma unroll
  for (int m = 32; m; m >>= 1) v += __shfl_xor(v, m, 64);
  return v;
}

// ---------------------------------------------------------------------------
// GEMM:  C[M,N] = A[M,K] @ B[N,K]^T (+bias[N])
// OMODE: 0=f32, 1=bf16
// ---------------------------------------------------------------------------
constexpr int BM = 128, BN = 128, BK = 64;

template<bool SPLIT, int OMODE>
__global__ __launch_bounds__(256)
void k_gemm_bt(const u16* __restrict__ Ah, const u16* __restrict__ Al, long lda,
               const u16* __restrict__ Bh, const u16* __restrict__ Bl, long ldb,
               const float* __restrict__ bias,
               float* __restrict__ Cf, u16* __restrict__ Cb, u16* __restrict__ Cl,
               long ldc, int K)
{
  __shared__ u16 lds[(SPLIT ? 4 : 2) * BM * BK];
  const int tid = threadIdx.x;
  const long arow0 = (long)blockIdx.y * BM;
  const long bcol0 = (long)blockIdx.x * BN;

  long offA[4], offB[4];
#pragma unroll
  for (int r = 0; r < 4; ++r) {
    const int off = r * 4096 + tid * 16;
    const int row = off >> 7;
    const int colb = off & 127;
    offA[r] = (arow0 + row) * lda + (colb >> 1);
    offB[r] = (bcol0 + row) * ldb + (colb >> 1);
  }

  const int lane = tid & 63;
  const int wid = tid >> 6;
  const int wr = (wid >> 1) * 64;
  const int wc = (wid & 1) * 64;
  const int fr = lane & 15;
  const int fk = (lane >> 4) * 8;

  f32x4 acc[4][4] = {};

  for (int k0 = 0; k0 < K; k0 += BK) {
#pragma unroll
    for (int r = 0; r < 4; ++r) {
      const int loff = (r * 4096 + tid * 16) >> 1;
      async16(&lds[loff],           Ah + offA[r] + k0);
      async16(&lds[BM*BK + loff],   Bh + offB[r] + k0);
      if constexpr (SPLIT) {
        async16(&lds[2*BM*BK + loff], Al + offA[r] + k0);
        async16(&lds[3*BM*BK + loff], Bl + offB[r] + k0);
      }
    }
    __syncthreads();
#pragma unroll
    for (int kk = 0; kk < BK; kk += 32) {
      s16x8 a[4], b[4];
#pragma unroll
      for (int m = 0; m < 4; ++m)
        a[m] = *(const s16x8*)&lds[(wr + m*16 + fr) * BK + kk + fk];
#pragma unroll
      for (int n = 0; n < 4; ++n)
        b[n] = *(const s16x8*)&lds[BM*BK + (wc + n*16 + fr) * BK + kk + fk];
#pragma unroll
      for (int m = 0; m < 4; ++m)
#pragma unroll
        for (int n = 0; n < 4; ++n)
          acc[m][n] = __builtin_amdgcn_mfma_f32_16x16x32_bf16(a[m], b[n], acc[m][n], 0, 0, 0);
      if constexpr (SPLIT) {
        s16x8 al[4], bl[4];
#pragma unroll
        for (int m = 0; m < 4; ++m)
          al[m] = *(const s16x8*)&lds[2*BM*BK + (wr + m*16 + fr) * BK + kk + fk];
#pragma unroll
        for (int n = 0; n < 4; ++n)
          bl[n] = *(const s16x8*)&lds[3*BM*BK + (wc + n*16 + fr) * BK + kk + fk];
#pragma unroll
        for (int m = 0; m < 4; ++m)
#pragma unroll
          for (int n = 0; n < 4; ++n) {
            acc[m][n] = __builtin_amdgcn_mfma_f32_16x16x32_bf16(a[m], bl[n], acc[m][n], 0, 0, 0);
            acc[m][n] = __builtin_amdgcn_mfma_f32_16x16x32_bf16(al[m], b[n], acc[m][n], 0, 0, 0);
          }
      }
    }
    __syncthreads();
  }

  float bv[4];
#pragma unroll
  for (int n = 0; n < 4; ++n) {
    const long gcol = bcol0 + wc + n*16 + fr;
    bv[n] = bias ? bias[gcol] : 0.f;
  }

#pragma unroll
  for (int m = 0; m < 4; ++m) {
#pragma unroll
    for (int reg = 0; reg < 4; ++reg) {
      const long grow = arow0 + wr + m*16 + (lane >> 4) * 4 + reg;
      const long ro = grow * ldc;
#pragma unroll
      for (int n = 0; n < 4; ++n) {
        const long gcol = bcol0 + wc + n*16 + fr;
        const float val = acc[m][n][reg] + bv[n];
        if constexpr (OMODE == 0) {
          Cf[ro + gcol] = val;
        } else {
          Cb[ro + gcol] = f2b(val);
        }
      }
    }
  }
}

// ---------------------------------------------------------------------------
// h GEMM (e @ w1 + b1) -> h bf16 [16384][2048], plus per-row LN partials
// (sum, sumsq over this block's 64-col span per wave) into pS/pQ[32][16384].
// ---------------------------------------------------------------------------
__global__ __launch_bounds__(256)
void k_gemm_h(const u16* __restrict__ Ah, const u16* __restrict__ Bh,
              const float* __restrict__ bias, u16* __restrict__ Cb,
              float* __restrict__ pS, float* __restrict__ pQ)
{
  __shared__ u16 lds[2 * BM * BK];
  const int tid = threadIdx.x;
  const long arow0 = (long)blockIdx.y * BM;
  const long bcol0 = (long)blockIdx.x * BN;

  long offA[4], offB[4];
#pragma unroll
  for (int r = 0; r < 4; ++r) {
    const int off = r * 4096 + tid * 16;
    const int row = off >> 7;
    const int colb = off & 127;
    offA[r] = (arow0 + row) * 256 + (colb >> 1);
    offB[r] = (bcol0 + row) * 256 + (colb >> 1);
  }

  const int lane = tid & 63;
  const int wid = tid >> 6;
  const int wr = (wid >> 1) * 64;
  const int wc = (wid & 1) * 64;
  const int fr = lane & 15;
  const int fk = (lane >> 4) * 8;

  f32x4 acc[4][4] = {};

  for (int k0 = 0; k0 < 256; k0 += BK) {
#pragma unroll
    for (int r = 0; r < 4; ++r) {
      const int loff = (r * 4096 + tid * 16) >> 1;
      async16(&lds[loff],         Ah + offA[r] + k0);
      async16(&lds[BM*BK + loff], Bh + offB[r] + k0);
    }
    __syncthreads();
#pragma unroll
    for (int kk = 0; kk < BK; kk += 32) {
      s16x8 a[4], b[4];
#pragma unroll
      for (int m = 0; m < 4; ++m)
        a[m] = *(const s16x8*)&lds[(wr + m*16 + fr) * BK + kk + fk];
#pragma unroll
      for (int n = 0; n < 4; ++n)
        b[n] = *(const s16x8*)&lds[BM*BK + (wc + n*16 + fr) * BK + kk + fk];
#pragma unroll
      for (int m = 0; m < 4; ++m)
#pragma unroll
        for (int n = 0; n < 4; ++n)
          acc[m][n] = __builtin_amdgcn_mfma_f32_16x16x32_bf16(a[m], b[n], acc[m][n], 0, 0, 0);
    }
    __syncthreads();
  }

  float bv[4];
#pragma unroll
  for (int n = 0; n < 4; ++n)
    bv[n] = bias[bcol0 + wc + n*16 + fr];

  const int slot = blockIdx.x * 2 + (wid & 1);
#pragma unroll
  for (int m = 0; m < 4; ++m) {
#pragma unroll
    for (int reg = 0; reg < 4; ++reg) {
      const long grow = arow0 + wr + m*16 + (lane >> 4) * 4 + reg;
      const long ro = grow * 2048;
      float s = 0.f, q = 0.f;
#pragma unroll
      for (int n = 0; n < 4; ++n) {
        const long gcol = bcol0 + wc + n*16 + fr;
        const float val = acc[m][n][reg] + bv[n];
        Cb[ro + gcol] = f2b(val);
        s += val; q += val * val;
      }
#pragma unroll
      for (int msk = 1; msk < 16; msk <<= 1) {
        s += __shfl_xor(s, msk, 64);
        q += __shfl_xor(q, msk, 64);
      }
      if ((lane & 15) == 0) {
        pS[(long)slot * 16384 + grow] = s;
        pQ[(long)slot * 16384 + grow] = q;
      }
    }
  }
}

// combine 32 partial slots -> per-row mu, rsqrt(var+eps)
__global__ __launch_bounds__(256)
void k_ln_stats(const float* __restrict__ pS, const float* __restrict__ pQ,
                float* __restrict__ smu, float* __restrict__ srs)
{
  const long row = (long)blockIdx.x * 256 + threadIdx.x;
  float s = 0.f, q = 0.f;
#pragma unroll
  for (int i = 0; i < 32; ++i) {
    s += pS[(long)i * 16384 + row];
    q += pQ[(long)i * 16384 + row];
  }
  const float mu = s * (1.f / 2048.f);
  const float var = q * (1.f / 2048.f) - mu * mu;
  smu[row] = mu;
  srs[row] = rsqrtf(var + 1e-5f);
}

// ---------------------------------------------------------------------------
// w2 GEMM: logits = leaky(LN(h)) @ w2 + b2.  A = h bf16 [16384][2048] with
// LN+leaky applied on the fly during A staging (reg-staged); mu/rs hoisted
// per-row. B = w2T bf16 [256][2048] via global_load_lds. Out f32.
// ---------------------------------------------------------------------------
__global__ __launch_bounds__(256)
void k_gemm_w2(const u16* __restrict__ Ah, const float* __restrict__ smu,
               const float* __restrict__ srs, const float* __restrict__ lg,
               const float* __restrict__ lb, const u16* __restrict__ Bh,
               const float* __restrict__ bias, float* __restrict__ Cf)
{
  __shared__ u16 ldsA[BM * BK];
  __shared__ u16 ldsB[BN * BK];
  const int tid = threadIdx.x;
  const long arow0 = (long)blockIdx.y * BM;
  const long bcol0 = (long)blockIdx.x * BN;

  // per-thread A staging geometry (4 rounds, fixed rows across k-tiles)
  int arow[4]; int acol[4];
  float mu4[4], rs4[4];
#pragma unroll
  for (int r = 0; r < 4; ++r) {
    const int off = r * 4096 + tid * 16;
    arow[r] = off >> 7;              // 0..127
    acol[r] = (off & 127) >> 1;      // 0..63, step 8
    mu4[r] = smu[arow0 + arow[r]];
    rs4[r] = srs[arow0 + arow[r]];
  }
  long offB[4];
#pragma unroll
  for (int r = 0; r < 4; ++r) {
    const int off = r * 4096 + tid * 16;
    offB[r] = (bcol0 + (off >> 7)) * 2048 + ((off & 127) >> 1);
  }

  const int lane = tid & 63;
  const int wid = tid >> 6;
  const int wr = (wid >> 1) * 64;
  const int wc = (wid & 1) * 64;
  const int fr = lane & 15;
  const int fk = (lane >> 4) * 8;

  f32x4 acc[4][4] = {};

  for (int k0 = 0; k0 < 2048; k0 += BK) {
    // B via async direct-to-LDS
#pragma unroll
    for (int r = 0; r < 4; ++r)
      async16(&ldsB[(r * 4096 + tid * 16) >> 1], Bh + offB[r] + k0);
    // A reg-staged with LN + leaky
#pragma unroll
    for (int r = 0; r < 4; ++r) {
      const u16x8 hv = *(const u16x8*)(Ah + (long)(arow0 + arow[r]) * 2048 + k0 + acol[r]);
      const float4 g0 = *(const float4*)(lg + k0 + acol[r]);
      const float4 g1 = *(const float4*)(lg + k0 + acol[r] + 4);
      const float4 b0 = *(const float4*)(lb + k0 + acol[r]);
      const float4 b1 = *(const float4*)(lb + k0 + acol[r] + 4);
      const float gg[8] = {g0.x, g0.y, g0.z, g0.w, g1.x, g1.y, g1.z, g1.w};
      const float bb[8] = {b0.x, b0.y, b0.z, b0.w, b1.x, b1.y, b1.z, b1.w};
      u16x8 o;
#pragma unroll
      for (int j = 0; j < 8; ++j) {
        float y = (b2f(hv[j]) - mu4[r]) * rs4[r] * gg[j] + bb[j];
        y = y > 0.f ? y : 0.01f * y;
        o[j] = f2b(y);
      }
      *(u16x8*)&ldsA[(r * 4096 + tid * 16) >> 1] = o;
    }
    __syncthreads();
#pragma unroll
    for (int kk = 0; kk < BK; kk += 32) {
      s16x8 a[4], b[4];
#pragma unroll
      for (int m = 0; m < 4; ++m)
        a[m] = *(const s16x8*)&ldsA[(wr + m*16 + fr) * BK + kk + fk];
#pragma unroll
      for (int n = 0; n < 4; ++n)
        b[n] = *(const s16x8*)&ldsB[(wc + n*16 + fr) * BK + kk + fk];
#pragma unroll
      for (int m = 0; m < 4; ++m)
#pragma unroll
        for (int n = 0; n < 4; ++n)
          acc[m][n] = __builtin_amdgcn_mfma_f32_16x16x32_bf16(a[m], b[n], acc[m][n], 0, 0, 0);
    }
    __syncthreads();
  }

  float bv[4];
#pragma unroll
  for (int n = 0; n < 4; ++n)
    bv[n] = bias[bcol0 + wc + n*16 + fr];

#pragma unroll
  for (int m = 0; m < 4; ++m) {
#pragma unroll
    for (int reg = 0; reg < 4; ++reg) {
      const long grow = arow0 + wr + m*16 + (lane >> 4) * 4 + reg;
      const long ro = grow * 256;
#pragma unroll
      for (int n = 0; n < 4; ++n) {
        const long gcol = bcol0 + wc + n*16 + fr;
        Cf[ro + gcol] = acc[m][n][reg] + bv[n];
      }
    }
  }
}

// ---------------------------------------------------------------------------
// Fused QKV GEMM with f32 A (x) staged directly; A converted to bf16 hi/lo
// on the fly via v_cvt_pk_bf16_f32. 3-product split numerics.
// ---------------------------------------------------------------------------
__global__ __launch_bounds__(256)
void k_gemm_qkv(const float* __restrict__ Af,   // x [16384][256] f32
                const u16* __restrict__ Bh, const u16* __restrict__ Bl,
                const float* __restrict__ bias, // catBias[768]
                u16* __restrict__ Cq, u16* __restrict__ Ck, u16* __restrict__ Cv)
{
  __shared__ float ldsA[BM * BK];   // 32KB
  __shared__ u16 ldsBh[BN * BK];    // 16KB
  __shared__ u16 ldsBl[BN * BK];    // 16KB
  const int tid = threadIdx.x;
  const long arow0 = (long)blockIdx.y * BM;
  const long bcol0 = (long)blockIdx.x * BN;

  long offA[8];
#pragma unroll
  for (int r = 0; r < 8; ++r) {
    const int off = r * 4096 + tid * 16;   // byte in 32KB A tile
    const int row = off >> 8;              // 256B per row (64 f32)
    const int colb = off & 255;
    offA[r] = (arow0 + row) * 256 + (colb >> 2);
  }
  long offB[4];
#pragma unroll
  for (int r = 0; r < 4; ++r) {
    const int off = r * 4096 + tid * 16;
    const int row = off >> 7;
    const int colb = off & 127;
    offB[r] = (bcol0 + row) * 256 + (colb >> 1);
  }

  const int lane = tid & 63;
  const int wid = tid >> 6;
  const int wr = (wid >> 1) * 64;
  const int wc = (wid & 1) * 64;
  const int fr = lane & 15;
  const int fk = (lane >> 4) * 8;

  f32x4 acc[4][4] = {};

  for (int k0 = 0; k0 < 256; k0 += BK) {
#pragma unroll
    for (int r = 0; r < 8; ++r)
      async16((char*)ldsA + r*4096 + tid*16, Af + offA[r] + k0);
#pragma unroll
    for (int r = 0; r < 4; ++r) {
      const int loff = (r * 4096 + tid * 16) >> 1;
      async16(&ldsBh[loff], Bh + offB[r] + k0);
      async16(&ldsBl[loff], Bl + offB[r] + k0);
    }
    __syncthreads();
#pragma unroll
    for (int kk = 0; kk < BK; kk += 32) {
      s16x8 a[4], al[4];
#pragma unroll
      for (int m = 0; m < 4; ++m) {
        const float* ap = &ldsA[(wr + m*16 + fr) * BK + kk + fk];
        const float4 v0 = *(const float4*)ap;
        const float4 v1 = *(const float4*)(ap + 4);
        u32x4 H, L;
        H[0] = cvtpk(v0.x, v0.y); H[1] = cvtpk(v0.z, v0.w);
        H[2] = cvtpk(v1.x, v1.y); H[3] = cvtpk(v1.z, v1.w);
        L[0] = cvtpk(v0.x - __builtin_bit_cast(float, H[0] << 16),
                     v0.y - __builtin_bit_cast(float, H[0] & 0xffff0000u));
        L[1] = cvtpk(v0.z - __builtin_bit_cast(float, H[1] << 16),
                     v0.w - __builtin_bit_cast(float, H[1] & 0xffff0000u));
        L[2] = cvtpk(v1.x - __builtin_bit_cast(float, H[2] << 16),
                     v1.y - __builtin_bit_cast(float, H[2] & 0xffff0000u));
        L[3] = cvtpk(v1.z - __builtin_bit_cast(float, H[3] << 16),
                     v1.w - __builtin_bit_cast(float, H[3] & 0xffff0000u));
        a[m]  = __builtin_bit_cast(s16x8, H);
        al[m] = __builtin_bit_cast(s16x8, L);
      }
      s16x8 b[4], bl[4];
#pragma unroll
      for (int n = 0; n < 4; ++n) {
        b[n]  = *(const s16x8*)&ldsBh[(wc + n*16 + fr) * BK + kk + fk];
        bl[n] = *(const s16x8*)&ldsBl[(wc + n*16 + fr) * BK + kk + fk];
      }
#pragma unroll
      for (int m = 0; m < 4; ++m)
#pragma unroll
        for (int n = 0; n < 4; ++n) {
          acc[m][n] = __builtin_amdgcn_mfma_f32_16x16x32_bf16(a[m],  b[n],  acc[m][n], 0, 0, 0);
          acc[m][n] = __builtin_amdgcn_mfma_f32_16x16x32_bf16(a[m],  bl[n], acc[m][n], 0, 0, 0);
          acc[m][n] = __builtin_amdgcn_mfma_f32_16x16x32_bf16(al[m], b[n],  acc[m][n], 0, 0, 0);
        }
    }
    __syncthreads();
  }

  float bv[4];
#pragma unroll
  for (int n = 0; n < 4; ++n)
    bv[n] = bias[bcol0 + wc + n*16 + fr];

  const int band = (int)(bcol0 >> 8);   // 0=q,1=k,2=v (block-uniform)
  u16* dst = (band == 0) ? Cq : (band == 1) ? Ck : Cv;

#pragma unroll
  for (int m = 0; m < 4; ++m) {
#pragma unroll
    for (int reg = 0; reg < 4; ++reg) {
      const long grow = arow0 + wr + m*16 + (lane >> 4) * 4 + reg;
#pragma unroll
      for (int n = 0; n < 4; ++n) {
        const long lc = bcol0 - (long)band*256 + wc + n*16 + fr;
        const float val = acc[m][n][reg] + bv[n];
        dst[grow * 256 + lc] = (band < 2) ? f2h(val) : f2b(val);
      }
    }
  }
}

// ---------------------------------------------------------------------------
// Flash attention v9: KSTEP=64, fp16 Q/K single product, double-buffered
// 32KB K tiles, fused LN(x + attn) epilogue writing ln1 bf16 directly.
// ---------------------------------------------------------------------------
__global__ __launch_bounds__(256)
void k_flash(const u16* __restrict__ q16, const u16* __restrict__ k16,
             const u16* __restrict__ vt,   // [256][4096] per batch (V^T), bf16
             const float* __restrict__ x,  // [4][4096][256] f32
             const float* __restrict__ g, const float* __restrict__ b,
             u16* __restrict__ ln1)        // [4][4096][256] bf16
{
  __shared__ u16 lkh[2][64*256];  // 64KB: K fp16 tiles, 512B rows, swizzled
  __shared__ float lS[32*68];     // S tile fp32, padded rows (272B); reused for LN
  __shared__ u16 lP[32*72];       // P bf16, rows padded to 144B
  __shared__ float lm[32], ll[32], lsc[32];

  const int tid = threadIdx.x;
  const int lane = tid & 63, wid = tid >> 6;
  const long bo = (long)blockIdx.y * 1048576;   // batch offset (elements)
  const long q0 = (long)blockIdx.x * 32;

  const int fr  = lane & 15;
  const int hi2 = lane >> 4;
  const int fk  = hi2 * 8;
  const int qh_sel = wid >> 1;
  const int kh_sel = wid & 1;

  // Q fragments in registers (fp16)
  f16x8 qf[8];
  {
    const u16* qp = q16 + bo + (q0 + qh_sel*16 + fr) * 256;
#pragma unroll
    for (int c = 0; c < 8; ++c)
      qf[c] = *(const f16x8*)(qp + c*32 + fk);
  }

  if (tid < 32) { lm[tid] = -1e30f; ll[tid] = 0.f; }
  f32x4 acc[2][4] = {};

  const char* kp = (const char*)(k16 + bo);
  const u16* vbase = vt + bo;

  auto STAGE = [&](int k0s, int bsel) {
#pragma unroll
    for (int r = 0; r < 8; ++r) {
      const int L = r*4096 + tid*16;          // byte offset in 32KB tile
      const int row = L >> 9;                 // 0..63
      const int colb = L & 511;
      const long gb = (long)(k0s + row)*512 + (colb ^ ((row & 7) << 4));
      async16((char*)lkh[bsel] + L, kp + gb);
    }
  };

  STAGE(0, 0);
  __syncthreads();   // prologue: tile 0 staged (implicit vmcnt drain, once)

  int cur = 0;
  for (int k0 = 0; k0 < 4096; k0 += 64) {
    // --- V prefetch into regs: 2 k-slices x 4 d-tiles ---
    s16x8 vb[2][4];
#pragma unroll
    for (int ks = 0; ks < 2; ++ks)
#pragma unroll
      for (int j = 0; j < 4; ++j)
        vb[ks][j] = *(const s16x8*)(vbase + (long)(wid*64 + j*16 + fr)*4096 + k0 + ks*32 + fk);

    // --- stage next K tile into the other buffer ---
    if (k0 + 64 < 4096) STAGE(k0 + 64, cur ^ 1);

    // --- QK^T: wave covers 16q x 32k via two chains ---
    f32x4 s0 = {}, s1 = {};
    const int kc0 = kh_sel*32 + fr;           // chain0 k-row; chain1 = +16
    const int swz = (kc0 & 7) << 4;           // (kc0+16)&7 == kc0&7
#pragma unroll
    for (int c = 0; c < 8; ++c) {
      const int o = (c*64 + hi2*16) ^ swz;
      const f16x8 b0 = *(const f16x8*)((const char*)lkh[cur] + kc0*512 + o);
      const f16x8 b1 = *(const f16x8*)((const char*)lkh[cur] + (kc0 + 16)*512 + o);
      s0 = __builtin_amdgcn_mfma_f32_16x16x32_f16(qf[c], b0, s0, 0, 0, 0);
      s1 = __builtin_amdgcn_mfma_f32_16x16x32_f16(qf[c], b1, s1, 0, 0, 0);
    }
#pragma unroll
    for (int r = 0; r < 4; ++r) {
      const int srow = (qh_sel*16 + hi2*4 + r) * 68;
      lS[srow + kh_sel*32 + fr]      = s0[r];
      lS[srow + kh_sel*32 + 16 + fr] = s1[r];
    }
    __syncthreads();   // S visible (also drains next-tile stage, under QKT)

    // --- online softmax: thread t owns row t>>3, cols (t&7)*8 .. +8 ---
    {
      const int sr = tid >> 3;
      const int sc = (tid & 7) * 8;
      const float4 sv0 = *(const float4*)&lS[sr*68 + sc];
      const float4 sv1 = *(const float4*)&lS[sr*68 + sc + 4];
      float tmx = fmaxf(fmaxf(fmaxf(sv0.x, sv0.y), fmaxf(sv0.z, sv0.w)),
                        fmaxf(fmaxf(sv1.x, sv1.y), fmaxf(sv1.z, sv1.w)));
#pragma unroll
      for (int m = 1; m < 8; m <<= 1) tmx = fmaxf(tmx, __shfl_xor(tmx, m, 64));
      const float mold = lm[sr];
      const float mnew = fmaxf(mold, tmx);
      const float p0 = __expf(sv0.x - mnew), p1 = __expf(sv0.y - mnew);
      const float p2 = __expf(sv0.z - mnew), p3 = __expf(sv0.w - mnew);
      const float p4 = __expf(sv1.x - mnew), p5 = __expf(sv1.y - mnew);
      const float p6 = __expf(sv1.z - mnew), p7 = __expf(sv1.w - mnew);
      float ps = ((p0 + p1) + (p2 + p3)) + ((p4 + p5) + (p6 + p7));
#pragma unroll
      for (int m = 1; m < 8; m <<= 1) ps += __shfl_xor(ps, m, 64);
      const float scale = __expf(mold - mnew);
      if ((tid & 7) == 0) {
        lm[sr] = mnew;
        ll[sr] = ll[sr] * scale + ps;
        lsc[sr] = scale;
      }
      u16x8 pb;
      pb[0]=f2b(p0); pb[1]=f2b(p1); pb[2]=f2b(p2); pb[3]=f2b(p3);
      pb[4]=f2b(p4); pb[5]=f2b(p5); pb[6]=f2b(p6); pb[7]=f2b(p7);
      *(u16x8*)&lP[sr*72 + sc] = pb;
    }
    __syncthreads();   // P, lsc, ll visible

    // --- PV: rescale acc, then acc += P @ V over 2 k-slices ---
#pragma unroll
    for (int qm = 0; qm < 2; ++qm)
#pragma unroll
      for (int r = 0; r < 4; ++r) {
        const float s = lsc[qm*16 + hi2*4 + r];
#pragma unroll
        for (int j = 0; j < 4; ++j) acc[qm][j][r] *= s;
      }
#pragma unroll
    for (int qm = 0; qm < 2; ++qm)
#pragma unroll
      for (int ks = 0; ks < 2; ++ks) {
        const s16x8 pa = *(const s16x8*)&lP[(qm*16 + fr)*72 + ks*32 + fk];
#pragma unroll
        for (int j = 0; j < 4; ++j)
          acc[qm][j] = __builtin_amdgcn_mfma_f32_16x16x32_bf16(pa, vb[ks][j], acc[qm][j], 0, 0, 0);
      }
    cur ^= 1;
  }

  // ---- fused epilogue: t = x + attn/l;  ln1 = LN(t) ----
  __syncthreads();   // all lS/lP reads done; reuse lS for LN partials
  float gv4[4], bv4[4];
#pragma unroll
  for (int j = 0; j < 4; ++j) {
    gv4[j] = g[wid*64 + j*16 + fr];
    bv4[j] = b[wid*64 + j*16 + fr];
  }
  const float* xb = x + bo + q0*256;
#pragma unroll
  for (int qm = 0; qm < 2; ++qm)
#pragma unroll
    for (int r = 0; r < 4; ++r) {
      const int row = qm*16 + hi2*4 + r;
      const float inv = 1.0f / ll[row];
      const float* xp = xb + (long)row*256 + wid*64 + fr;
      float s = 0.f, qq = 0.f;
#pragma unroll
      for (int j = 0; j < 4; ++j) {
        const float t = acc[qm][j][r] * inv + xp[j*16];
        acc[qm][j][r] = t;
        s += t; qq += t*t;
      }
#pragma unroll
      for (int m = 1; m < 16; m <<= 1) {
        s  += __shfl_xor(s, m, 64);
        qq += __shfl_xor(qq, m, 64);
      }
      if (fr == 0) { lS[row*4 + wid] = s; lS[128 + row*4 + wid] = qq; }
    }
  __syncthreads();
#pragma unroll
  for (int qm = 0; qm < 2; ++qm)
#pragma unroll
    for (int r = 0; r < 4; ++r) {
      const int row = qm*16 + hi2*4 + r;
      const float s  = (lS[row*4+0] + lS[row*4+1]) + (lS[row*4+2] + lS[row*4+3]);
      const float qq = (lS[128+row*4+0] + lS[128+row*4+1]) + (lS[128+row*4+2] + lS[128+row*4+3]);
      const float mu = s * (1.f / 256.f);
      const float var = qq * (1.f / 256.f) - mu * mu;
      const float rs = rsqrtf(var + 1e-5f);
      u16* op = ln1 + bo + (q0 + row)*256 + wid*64 + fr;
#pragma unroll
      for (int j = 0; j < 4; ++j)
        op[j*16] = f2b((acc[qm][j][r] - mu) * rs * gv4[j] + bv4[j]);
    }
}

// --------------------------- prep / elementwise ----------------------------

// Fused transpose of wq/wk/wv (split, into concat B[768][256]) and w0
// (non-split). z==3 block(0,0) also builds the 768-entry concat bias.
__global__ __launch_bounds__(256)
void k_transpose_qkv0(const float* __restrict__ wq, const float* __restrict__ wk,
                      const float* __restrict__ wv, const float* __restrict__ w0,
                      u16* __restrict__ catT_h, u16* __restrict__ catT_l,
                      u16* __restrict__ w0T,
                      const float* __restrict__ bq, const float* __restrict__ bk,
                      const float* __restrict__ bv, float* __restrict__ catBias) {
  __shared__ float t[32][33];
  const int z = blockIdx.z;
  const float* in = (z == 0) ? wq : (z == 1) ? wk : (z == 2) ? wv : w0;
  const int c0 = blockIdx.x * 32, r0 = blockIdx.y * 32;
  const int tx = threadIdx.x, ty = threadIdx.y;
#pragma unroll
  for (int i = 0; i < 4; ++i)
    t[ty + i*8][tx] = in[(long)(r0 + ty + i*8) * 256 + c0 + tx];
  __syncthreads();
#pragma unroll
  for (int i = 0; i < 4; ++i) {
    const float f = t[tx][ty + i*8];
    const u16 hb = f2b(f);
    if (z < 3) {
      const long o = (long)(z*256 + c0 + ty + i*8) * 256 + r0 + tx;
      catT_h[o] = hb;
      catT_l[o] = f2b(f - b2f(hb));
    } else {
      w0T[(long)(c0 + ty + i*8) * 256 + r0 + tx] = hb;
    }
  }
  if (z == 3 && blockIdx.x == 0 && blockIdx.y == 0) {
    const int t0 = ty * 32 + tx;   // 0..255
    catBias[t0] = bq[t0];
    catBias[256 + t0] = bk[t0];
    catBias[512 + t0] = bv[t0];
  }
}

__global__ __launch_bounds__(256)
void k_transpose_f32ns(const float* __restrict__ in, u16* __restrict__ hi, int R, int C) {
  __shared__ float t[32][33];
  const int c0 = blockIdx.x * 32, r0 = blockIdx.y * 32;
  const int tx = threadIdx.x, ty = threadIdx.y;
#pragma unroll
  for (int i = 0; i < 4; ++i)
    t[ty + i*8][tx] = in[(long)(r0 + ty + i*8) * C + c0 + tx];
  __syncthreads();
#pragma unroll
  for (int i = 0; i < 4; ++i)
    hi[(long)(c0 + ty + i*8) * R + r0 + tx] = f2b(t[tx][ty + i*8]);
}

__global__ __launch_bounds__(256)
void k_transpose_bf16(const u16* __restrict__ in, u16* __restrict__ out,
                      int R, int C, long sIn, long sOut) {
  __shared__ u16 t[32][34];
  const int z = blockIdx.z;
  const u16* ib = in + (long)z * sIn;
  u16* ob = out + (long)z * sOut;
  const int c0 = blockIdx.x * 32, r0 = blockIdx.y * 32;
  const int tx = threadIdx.x, ty = threadIdx.y;
#pragma unroll
  for (int i = 0; i < 4; ++i)
    t[ty + i*8][tx] = ib[(long)(r0 + ty + i*8) * C + c0 + tx];
  __syncthreads();
#pragma unroll
  for (int i = 0; i < 4; ++i)
    ob[(long)(c0 + ty + i*8) * R + r0 + tx] = t[tx][ty + i*8];
}

// out = LN(leaky_relu(logits + e)) -> fp32.  e is bf16.
__global__ __launch_bounds__(256)
void k_final(const float* __restrict__ lg, const u16* __restrict__ e,
             const float* __restrict__ g, const float* __restrict__ b,
             float* __restrict__ out) {
  const long row = (long)blockIdx.x * 4 + (threadIdx.x >> 6);
  const int lane = threadIdx.x & 63;
  const long base = row * 256 + lane * 4;
  const float4 lv = *(const float4*)(lg + base);
  const u16x4 ev = *(const u16x4*)(e + base);
  float t[4] = {lv.x + b2f(ev[0]), lv.y + b2f(ev[1]), lv.z + b2f(ev[2]), lv.w + b2f(ev[3])};
#pragma unroll
  for (int j = 0; j < 4; ++j) t[j] = t[j] > 0.f ? t[j] : 0.01f * t[j];
  float s = t[0] + t[1] + t[2] + t[3];
  float q = t[0]*t[0] + t[1]*t[1] + t[2]*t[2] + t[3]*t[3];
  s = wave_sum(s); q = wave_sum(q);
  const float mu = s * (1.f / 256.f);
  const float var = q * (1.f / 256.f) - mu * mu;
  const float rs = rsqrtf(var + 1e-5f);
  const float4 gv = *(const float4*)(g + lane * 4);
  const float4 bv = *(const float4*)(b + lane * 4);
  float4 o;
  o.x = (t[0] - mu) * rs * gv.x + bv.x;
  o.y = (t[1] - mu) * rs * gv.y + bv.y;
  o.z = (t[2] - mu) * rs * gv.z + bv.z;
  o.w = (t[3] - mu) * rs * gv.w + bv.w;
  *(float4*)(out + base) = o;
}

// ---------------------------------------------------------------------------

extern "C" void kernel_launch(void* const* d_in, const int* in_sizes, int n_in,
                              void* d_out, int out_size, void* d_ws, size_t ws_size,
                              hipStream_t stream) {
  const float* x   = (const float*)d_in[0];
  const float* wq  = (const float*)d_in[1];
  const float* bq  = (const float*)d_in[2];
  const float* wk  = (const float*)d_in[3];
  const float* bk  = (const float*)d_in[4];
  const float* wv  = (const float*)d_in[5];
  const float* bv_ = (const float*)d_in[6];
  const float* w0  = (const float*)d_in[7];
  const float* b0  = (const float*)d_in[8];
  const float* w1  = (const float*)d_in[9];
  const float* b1  = (const float*)d_in[10];
  const float* lmg = (const float*)d_in[11];
  const float* lmb = (const float*)d_in[12];
  const float* w2  = (const float*)d_in[13];
  const float* b2  = (const float*)d_in[14];
  const float* l1g = (const float*)d_in[15];
  const float* l1b = (const float*)d_in[16];
  const float* l2g = (const float*)d_in[17];
  const float* l2b = (const float*)d_in[18];

  char* ws = (char*)d_ws;
  float* out = (float*)d_out;

  // ws layout; peak ~106.9 MiB.
  u16* q16    = (u16*)(ws + 0);            // fp16 [4][4096][256]
  u16* k16    = (u16*)(ws + 16777216);
  u16* vT     = (u16*)(ws + 33554432);
  u16* v_b    = (u16*)(ws + 58720256);     // dead after transpose
  float* pS   = (float*)(ws + 67108864);   // 2 MiB [32][16384]
  float* pQ   = (float*)(ws + 69206016);   // 2 MiB
  float* smu  = (float*)(ws + 71303168);   // 64 KiB
  float* srs  = (float*)(ws + 71368704);   // 64 KiB, ends 71434240
  u16* ln1    = (u16*)(ws + 75497472);
  u16* e_b    = (u16*)(ws + 83886080);
  float* logits = (float*)(ws + 92274688); // 16 MiB, ends 109051904
  u16* h_b    = (u16*)(ws + 0);            // 64 MiB over dead q16/k16/vT/v_b
  u16* catT_h = (u16*)(ws + 109051904);    // [768][256] bf16-hi of f32 weights
  u16* catT_l = (u16*)(ws + 109445120);
  u16* w0T    = (u16*)(ws + 109838336);
  u16* w1T    = (u16*)(ws + 109969408);
  u16* w2T    = (u16*)(ws + 111017984);
  float* catBias = (float*)(ws + 112066560); // 768 f32, ends 112069632

  const dim3 t256(256);
  const dim3 tr(32, 8);

  // prep: fused transpose wq/wk/wv(+concat bias)/w0; w1; w2
  k_transpose_qkv0<<<dim3(8, 8, 4), tr, 0, stream>>>(
      wq, wk, wv, w0, catT_h, catT_l, w0T, bq, bk, bv_, catBias);
  k_transpose_f32ns<<<dim3(64, 8), tr, 0, stream>>>(w1, w1T, 256, 2048);
  k_transpose_f32ns<<<dim3(8, 64), tr, 0, stream>>>(w2, w2T, 2048, 256);

  // fused QKV projection: f32 x staged directly, converted in-kernel
  k_gemm_qkv<<<dim3(6, 128), t256, 0, stream>>>(
      x, catT_h, catT_l, catBias, q16, k16, v_b);
  k_transpose_bf16<<<dim3(8, 128, 4), tr, 0, stream>>>(v_b, vT, 4096, 256, 1048576, 1048576);

  // fused flash attention + LN(x+attn) epilogue -> ln1
  k_flash<<<dim3(128, 4), t256, 0, stream>>>(q16, k16, vT, x, l1g, l1b, ln1);

  // e = ln1 @ w0 + b0 (bf16)
  k_gemm_bt<false, 1><<<dim3(2, 128), t256, 0, stream>>>(
      ln1, nullptr, 256, w0T, nullptr, 256, b0, nullptr, e_b, nullptr, 256, 256);
  // h = e @ w1 + b1 (bf16 + LN partials; overlays dead q/k/v region)
  k_gemm_h<<<dim3(16, 128), t256, 0, stream>>>(e_b, w1T, b1, h_b, pS, pQ);
  // per-row LN stats for h
  k_ln_stats<<<64, t256, 0, stream>>>(pS, pQ, smu, srs);
  // logits = leaky(LN(h)) @ w2 + b2 (LN fused into A staging)
  k_gemm_w2<<<dim3(2, 128), t256, 0, stream>>>(
      h_b, smu, srs, lmg, lmb, w2T, b2, logits);
  k_final<<<4096, t256, 0, stream>>>(logits, e_b, l2g, l2b, out);
}

// Round 22
// 334.135 us; speedup vs baseline: 1.0306x; 1.0306x over previous
//
#include <hip/hip_runtime.h>

typedef unsigned short u16;
typedef unsigned int   u32;
typedef u16   u16x4 __attribute__((ext_vector_type(4)));
typedef u16   u16x8 __attribute__((ext_vector_type(8)));
typedef short s16x8 __attribute__((ext_vector_type(8)));
typedef u32   u32x4 __attribute__((ext_vector_type(4)));
typedef float f32x4 __attribute__((ext_vector_type(4)));
typedef _Float16 f16x8 __attribute__((ext_vector_type(8)));

__device__ __forceinline__ u16 f2b(float f) {
  u32 u = __builtin_bit_cast(u32, f);
  u32 r = (u + 0x7fffu + ((u >> 16) & 1u)) >> 16;
  return (u16)r;
}
__device__ __forceinline__ float b2f(u16 h) {
  return __builtin_bit_cast(float, (u32)h << 16);
}
__device__ __forceinline__ u16 f2h(float f) {
  _Float16 h = (_Float16)f;           // v_cvt_f16_f32 (RNE)
  return __builtin_bit_cast(u16, h);
}
__device__ __forceinline__ u32 cvtpk(float a, float b) {  // low16=bf16(a), high16=bf16(b)
  u32 r; asm("v_cvt_pk_bf16_f32 %0, %1, %2" : "=v"(r) : "v"(a), "v"(b)); return r;
}

__device__ __forceinline__ void async16(void* l, const void* g) {
  __builtin_amdgcn_global_load_lds((const __attribute__((address_space(1))) u32*)g,
                                   (__attribute__((address_space(3))) u32*)l, 16, 0, 0);
}

__device__ __forceinline__ float wave_sum(float v) {
#pragma unroll
  for (int m = 32; m; m >>= 1) v += __shfl_xor(v, m, 64);
  return v;
}

// ---------------------------------------------------------------------------
// GEMM:  C[M,N] = A[M,K] @ B[N,K]^T (+bias[N])
// OMODE: 0=f32, 1=bf16
// ---------------------------------------------------------------------------
constexpr int BM = 128, BN = 128, BK = 64;

template<bool SPLIT, int OMODE>
__global__ __launch_bounds__(256)
void k_gemm_bt(const u16* __restrict__ Ah, const u16* __restrict__ Al, long lda,
               const u16* __restrict__ Bh, const u16* __restrict__ Bl, long ldb,
               const float* __restrict__ bias,
               float* __restrict__ Cf, u16* __restrict__ Cb, u16* __restrict__ Cl,
               long ldc, int K)
{
  __shared__ u16 lds[(SPLIT ? 4 : 2) * BM * BK];
  const int tid = threadIdx.x;
  const long arow0 = (long)blockIdx.y * BM;
  const long bcol0 = (long)blockIdx.x * BN;

  long offA[4], offB[4];
#pragma unroll
  for (int r = 0; r < 4; ++r) {
    const int off = r * 4096 + tid * 16;
    const int row = off >> 7;
    const int colb = off & 127;
    offA[r] = (arow0 + row) * lda + (colb >> 1);
    offB[r] = (bcol0 + row) * ldb + (colb >> 1);
  }

  const int lane = tid & 63;
  const int wid = tid >> 6;
  const int wr = (wid >> 1) * 64;
  const int wc = (wid & 1) * 64;
  const int fr = lane & 15;
  const int fk = (lane >> 4) * 8;

  f32x4 acc[4][4] = {};

  for (int k0 = 0; k0 < K; k0 += BK) {
#pragma unroll
    for (int r = 0; r < 4; ++r) {
      const int loff = (r * 4096 + tid * 16) >> 1;
      async16(&lds[loff],           Ah + offA[r] + k0);
      async16(&lds[BM*BK + loff],   Bh + offB[r] + k0);
      if constexpr (SPLIT) {
        async16(&lds[2*BM*BK + loff], Al + offA[r] + k0);
        async16(&lds[3*BM*BK + loff], Bl + offB[r] + k0);
      }
    }
    __syncthreads();
#pragma unroll
    for (int kk = 0; kk < BK; kk += 32) {
      s16x8 a[4], b[4];
#pragma unroll
      for (int m = 0; m < 4; ++m)
        a[m] = *(const s16x8*)&lds[(wr + m*16 + fr) * BK + kk + fk];
#pragma unroll
      for (int n = 0; n < 4; ++n)
        b[n] = *(const s16x8*)&lds[BM*BK + (wc + n*16 + fr) * BK + kk + fk];
#pragma unroll
      for (int m = 0; m < 4; ++m)
#pragma unroll
        for (int n = 0; n < 4; ++n)
          acc[m][n] = __builtin_amdgcn_mfma_f32_16x16x32_bf16(a[m], b[n], acc[m][n], 0, 0, 0);
      if constexpr (SPLIT) {
        s16x8 al[4], bl[4];
#pragma unroll
        for (int m = 0; m < 4; ++m)
          al[m] = *(const s16x8*)&lds[2*BM*BK + (wr + m*16 + fr) * BK + kk + fk];
#pragma unroll
        for (int n = 0; n < 4; ++n)
          bl[n] = *(const s16x8*)&lds[3*BM*BK + (wc + n*16 + fr) * BK + kk + fk];
#pragma unroll
        for (int m = 0; m < 4; ++m)
#pragma unroll
          for (int n = 0; n < 4; ++n) {
            acc[m][n] = __builtin_amdgcn_mfma_f32_16x16x32_bf16(a[m], bl[n], acc[m][n], 0, 0, 0);
            acc[m][n] = __builtin_amdgcn_mfma_f32_16x16x32_bf16(al[m], b[n], acc[m][n], 0, 0, 0);
          }
      }
    }
    __syncthreads();
  }

  float bv[4];
#pragma unroll
  for (int n = 0; n < 4; ++n) {
    const long gcol = bcol0 + wc + n*16 + fr;
    bv[n] = bias ? bias[gcol] : 0.f;
  }

#pragma unroll
  for (int m = 0; m < 4; ++m) {
#pragma unroll
    for (int reg = 0; reg < 4; ++reg) {
      const long grow = arow0 + wr + m*16 + (lane >> 4) * 4 + reg;
      const long ro = grow * ldc;
#pragma unroll
      for (int n = 0; n < 4; ++n) {
        const long gcol = bcol0 + wc + n*16 + fr;
        const float val = acc[m][n][reg] + bv[n];
        if constexpr (OMODE == 0) {
          Cf[ro + gcol] = val;
        } else {
          Cb[ro + gcol] = f2b(val);
        }
      }
    }
  }
}

// ---------------------------------------------------------------------------
// Fused QKV GEMM with f32 A (x) staged directly; A converted to bf16 hi/lo
// on the fly via v_cvt_pk_bf16_f32. 3-product split numerics.
// ---------------------------------------------------------------------------
__global__ __launch_bounds__(256)
void k_gemm_qkv(const float* __restrict__ Af,   // x [16384][256] f32
                const u16* __restrict__ Bh, const u16* __restrict__ Bl,
                const float* __restrict__ bias, // catBias[768]
                u16* __restrict__ Cq, u16* __restrict__ Ck, u16* __restrict__ Cv)
{
  __shared__ float ldsA[BM * BK];   // 32KB
  __shared__ u16 ldsBh[BN * BK];    // 16KB
  __shared__ u16 ldsBl[BN * BK];    // 16KB
  const int tid = threadIdx.x;
  const long arow0 = (long)blockIdx.y * BM;
  const long bcol0 = (long)blockIdx.x * BN;

  long offA[8];
#pragma unroll
  for (int r = 0; r < 8; ++r) {
    const int off = r * 4096 + tid * 16;   // byte in 32KB A tile
    const int row = off >> 8;              // 256B per row (64 f32)
    const int colb = off & 255;
    offA[r] = (arow0 + row) * 256 + (colb >> 2);
  }
  long offB[4];
#pragma unroll
  for (int r = 0; r < 4; ++r) {
    const int off = r * 4096 + tid * 16;
    const int row = off >> 7;
    const int colb = off & 127;
    offB[r] = (bcol0 + row) * 256 + (colb >> 1);
  }

  const int lane = tid & 63;
  const int wid = tid >> 6;
  const int wr = (wid >> 1) * 64;
  const int wc = (wid & 1) * 64;
  const int fr = lane & 15;
  const int fk = (lane >> 4) * 8;

  f32x4 acc[4][4] = {};

  for (int k0 = 0; k0 < 256; k0 += BK) {
#pragma unroll
    for (int r = 0; r < 8; ++r)
      async16((char*)ldsA + r*4096 + tid*16, Af + offA[r] + k0);
#pragma unroll
    for (int r = 0; r < 4; ++r) {
      const int loff = (r * 4096 + tid * 16) >> 1;
      async16(&ldsBh[loff], Bh + offB[r] + k0);
      async16(&ldsBl[loff], Bl + offB[r] + k0);
    }
    __syncthreads();
#pragma unroll
    for (int kk = 0; kk < BK; kk += 32) {
      s16x8 a[4], al[4];
#pragma unroll
      for (int m = 0; m < 4; ++m) {
        const float* ap = &ldsA[(wr + m*16 + fr) * BK + kk + fk];
        const float4 v0 = *(const float4*)ap;
        const float4 v1 = *(const float4*)(ap + 4);
        u32x4 H, L;
        H[0] = cvtpk(v0.x, v0.y); H[1] = cvtpk(v0.z, v0.w);
        H[2] = cvtpk(v1.x, v1.y); H[3] = cvtpk(v1.z, v1.w);
        L[0] = cvtpk(v0.x - __builtin_bit_cast(float, H[0] << 16),
                     v0.y - __builtin_bit_cast(float, H[0] & 0xffff0000u));
        L[1] = cvtpk(v0.z - __builtin_bit_cast(float, H[1] << 16),
                     v0.w - __builtin_bit_cast(float, H[1] & 0xffff0000u));
        L[2] = cvtpk(v1.x - __builtin_bit_cast(float, H[2] << 16),
                     v1.y - __builtin_bit_cast(float, H[2] & 0xffff0000u));
        L[3] = cvtpk(v1.z - __builtin_bit_cast(float, H[3] << 16),
                     v1.w - __builtin_bit_cast(float, H[3] & 0xffff0000u));
        a[m]  = __builtin_bit_cast(s16x8, H);
        al[m] = __builtin_bit_cast(s16x8, L);
      }
      s16x8 b[4], bl[4];
#pragma unroll
      for (int n = 0; n < 4; ++n) {
        b[n]  = *(const s16x8*)&ldsBh[(wc + n*16 + fr) * BK + kk + fk];
        bl[n] = *(const s16x8*)&ldsBl[(wc + n*16 + fr) * BK + kk + fk];
      }
#pragma unroll
      for (int m = 0; m < 4; ++m)
#pragma unroll
        for (int n = 0; n < 4; ++n) {
          acc[m][n] = __builtin_amdgcn_mfma_f32_16x16x32_bf16(a[m],  b[n],  acc[m][n], 0, 0, 0);
          acc[m][n] = __builtin_amdgcn_mfma_f32_16x16x32_bf16(a[m],  bl[n], acc[m][n], 0, 0, 0);
          acc[m][n] = __builtin_amdgcn_mfma_f32_16x16x32_bf16(al[m], b[n],  acc[m][n], 0, 0, 0);
        }
    }
    __syncthreads();
  }

  float bv[4];
#pragma unroll
  for (int n = 0; n < 4; ++n)
    bv[n] = bias[bcol0 + wc + n*16 + fr];

  const int band = (int)(bcol0 >> 8);   // 0=q,1=k,2=v (block-uniform)
  u16* dst = (band == 0) ? Cq : (band == 1) ? Ck : Cv;

#pragma unroll
  for (int m = 0; m < 4; ++m) {
#pragma unroll
    for (int reg = 0; reg < 4; ++reg) {
      const long grow = arow0 + wr + m*16 + (lane >> 4) * 4 + reg;
#pragma unroll
      for (int n = 0; n < 4; ++n) {
        const long lc = bcol0 - (long)band*256 + wc + n*16 + fr;
        const float val = acc[m][n][reg] + bv[n];
        dst[grow * 256 + lc] = (band < 2) ? f2h(val) : f2b(val);
      }
    }
  }
}

// ---------------------------------------------------------------------------
// Flash attention v9: KSTEP=64, fp16 Q/K single product, double-buffered
// 32KB K tiles, fused LN(x + attn) epilogue writing ln1 bf16 directly.
// ---------------------------------------------------------------------------
__global__ __launch_bounds__(256)
void k_flash(const u16* __restrict__ q16, const u16* __restrict__ k16,
             const u16* __restrict__ vt,   // [256][4096] per batch (V^T), bf16
             const float* __restrict__ x,  // [4][4096][256] f32
             const float* __restrict__ g, const float* __restrict__ b,
             u16* __restrict__ ln1)        // [4][4096][256] bf16
{
  __shared__ u16 lkh[2][64*256];  // 64KB: K fp16 tiles, 512B rows, swizzled
  __shared__ float lS[32*68];     // S tile fp32, padded rows (272B); reused for LN
  __shared__ u16 lP[32*72];       // P bf16, rows padded to 144B
  __shared__ float lm[32], ll[32], lsc[32];

  const int tid = threadIdx.x;
  const int lane = tid & 63, wid = tid >> 6;
  const long bo = (long)blockIdx.y * 1048576;   // batch offset (elements)
  const long q0 = (long)blockIdx.x * 32;

  const int fr  = lane & 15;
  const int hi2 = lane >> 4;
  const int fk  = hi2 * 8;
  const int qh_sel = wid >> 1;
  const int kh_sel = wid & 1;

  // Q fragments in registers (fp16)
  f16x8 qf[8];
  {
    const u16* qp = q16 + bo + (q0 + qh_sel*16 + fr) * 256;
#pragma unroll
    for (int c = 0; c < 8; ++c)
      qf[c] = *(const f16x8*)(qp + c*32 + fk);
  }

  if (tid < 32) { lm[tid] = -1e30f; ll[tid] = 0.f; }
  f32x4 acc[2][4] = {};

  const char* kp = (const char*)(k16 + bo);
  const u16* vbase = vt + bo;

  auto STAGE = [&](int k0s, int bsel) {
#pragma unroll
    for (int r = 0; r < 8; ++r) {
      const int L = r*4096 + tid*16;          // byte offset in 32KB tile
      const int row = L >> 9;                 // 0..63
      const int colb = L & 511;
      const long gb = (long)(k0s + row)*512 + (colb ^ ((row & 7) << 4));
      async16((char*)lkh[bsel] + L, kp + gb);
    }
  };

  STAGE(0, 0);
  __syncthreads();   // prologue: tile 0 staged (implicit vmcnt drain, once)

  int cur = 0;
  for (int k0 = 0; k0 < 4096; k0 += 64) {
    // --- V prefetch into regs: 2 k-slices x 4 d-tiles ---
    s16x8 vb[2][4];
#pragma unroll
    for (int ks = 0; ks < 2; ++ks)
#pragma unroll
      for (int j = 0; j < 4; ++j)
        vb[ks][j] = *(const s16x8*)(vbase + (long)(wid*64 + j*16 + fr)*4096 + k0 + ks*32 + fk);

    // --- stage next K tile into the other buffer ---
    if (k0 + 64 < 4096) STAGE(k0 + 64, cur ^ 1);

    // --- QK^T: wave covers 16q x 32k via two chains ---
    f32x4 s0 = {}, s1 = {};
    const int kc0 = kh_sel*32 + fr;           // chain0 k-row; chain1 = +16
    const int swz = (kc0 & 7) << 4;           // (kc0+16)&7 == kc0&7
#pragma unroll
    for (int c = 0; c < 8; ++c) {
      const int o = (c*64 + hi2*16) ^ swz;
      const f16x8 b0 = *(const f16x8*)((const char*)lkh[cur] + kc0*512 + o);
      const f16x8 b1 = *(const f16x8*)((const char*)lkh[cur] + (kc0 + 16)*512 + o);
      s0 = __builtin_amdgcn_mfma_f32_16x16x32_f16(qf[c], b0, s0, 0, 0, 0);
      s1 = __builtin_amdgcn_mfma_f32_16x16x32_f16(qf[c], b1, s1, 0, 0, 0);
    }
#pragma unroll
    for (int r = 0; r < 4; ++r) {
      const int srow = (qh_sel*16 + hi2*4 + r) * 68;
      lS[srow + kh_sel*32 + fr]      = s0[r];
      lS[srow + kh_sel*32 + 16 + fr] = s1[r];
    }
    __syncthreads();   // S visible (also drains next-tile stage, under QKT)

    // --- online softmax: thread t owns row t>>3, cols (t&7)*8 .. +8 ---
    {
      const int sr = tid >> 3;
      const int sc = (tid & 7) * 8;
      const float4 sv0 = *(const float4*)&lS[sr*68 + sc];
      const float4 sv1 = *(const float4*)&lS[sr*68 + sc + 4];
      float tmx = fmaxf(fmaxf(fmaxf(sv0.x, sv0.y), fmaxf(sv0.z, sv0.w)),
                        fmaxf(fmaxf(sv1.x, sv1.y), fmaxf(sv1.z, sv1.w)));
#pragma unroll
      for (int m = 1; m < 8; m <<= 1) tmx = fmaxf(tmx, __shfl_xor(tmx, m, 64));
      const float mold = lm[sr];
      const float mnew = fmaxf(mold, tmx);
      const float p0 = __expf(sv0.x - mnew), p1 = __expf(sv0.y - mnew);
      const float p2 = __expf(sv0.z - mnew), p3 = __expf(sv0.w - mnew);
      const float p4 = __expf(sv1.x - mnew), p5 = __expf(sv1.y - mnew);
      const float p6 = __expf(sv1.z - mnew), p7 = __expf(sv1.w - mnew);
      float ps = ((p0 + p1) + (p2 + p3)) + ((p4 + p5) + (p6 + p7));
#pragma unroll
      for (int m = 1; m < 8; m <<= 1) ps += __shfl_xor(ps, m, 64);
      const float scale = __expf(mold - mnew);
      if ((tid & 7) == 0) {
        lm[sr] = mnew;
        ll[sr] = ll[sr] * scale + ps;
        lsc[sr] = scale;
      }
      u16x8 pb;
      pb[0]=f2b(p0); pb[1]=f2b(p1); pb[2]=f2b(p2); pb[3]=f2b(p3);
      pb[4]=f2b(p4); pb[5]=f2b(p5); pb[6]=f2b(p6); pb[7]=f2b(p7);
      *(u16x8*)&lP[sr*72 + sc] = pb;
    }
    __syncthreads();   // P, lsc, ll visible

    // --- PV: rescale acc, then acc += P @ V over 2 k-slices ---
#pragma unroll
    for (int qm = 0; qm < 2; ++qm)
#pragma unroll
      for (int r = 0; r < 4; ++r) {
        const float s = lsc[qm*16 + hi2*4 + r];
#pragma unroll
        for (int j = 0; j < 4; ++j) acc[qm][j][r] *= s;
      }
#pragma unroll
    for (int qm = 0; qm < 2; ++qm)
#pragma unroll
      for (int ks = 0; ks < 2; ++ks) {
        const s16x8 pa = *(const s16x8*)&lP[(qm*16 + fr)*72 + ks*32 + fk];
#pragma unroll
        for (int j = 0; j < 4; ++j)
          acc[qm][j] = __builtin_amdgcn_mfma_f32_16x16x32_bf16(pa, vb[ks][j], acc[qm][j], 0, 0, 0);
      }
    cur ^= 1;
  }

  // ---- fused epilogue: t = x + attn/l;  ln1 = LN(t) ----
  __syncthreads();   // all lS/lP reads done; reuse lS for LN partials
  float gv4[4], bv4[4];
#pragma unroll
  for (int j = 0; j < 4; ++j) {
    gv4[j] = g[wid*64 + j*16 + fr];
    bv4[j] = b[wid*64 + j*16 + fr];
  }
  const float* xb = x + bo + q0*256;
#pragma unroll
  for (int qm = 0; qm < 2; ++qm)
#pragma unroll
    for (int r = 0; r < 4; ++r) {
      const int row = qm*16 + hi2*4 + r;
      const float inv = 1.0f / ll[row];
      const float* xp = xb + (long)row*256 + wid*64 + fr;
      float s = 0.f, qq = 0.f;
#pragma unroll
      for (int j = 0; j < 4; ++j) {
        const float t = acc[qm][j][r] * inv + xp[j*16];
        acc[qm][j][r] = t;
        s += t; qq += t*t;
      }
#pragma unroll
      for (int m = 1; m < 16; m <<= 1) {
        s  += __shfl_xor(s, m, 64);
        qq += __shfl_xor(qq, m, 64);
      }
      if (fr == 0) { lS[row*4 + wid] = s; lS[128 + row*4 + wid] = qq; }
    }
  __syncthreads();
#pragma unroll
  for (int qm = 0; qm < 2; ++qm)
#pragma unroll
    for (int r = 0; r < 4; ++r) {
      const int row = qm*16 + hi2*4 + r;
      const float s  = (lS[row*4+0] + lS[row*4+1]) + (lS[row*4+2] + lS[row*4+3]);
      const float qq = (lS[128+row*4+0] + lS[128+row*4+1]) + (lS[128+row*4+2] + lS[128+row*4+3]);
      const float mu = s * (1.f / 256.f);
      const float var = qq * (1.f / 256.f) - mu * mu;
      const float rs = rsqrtf(var + 1e-5f);
      u16* op = ln1 + bo + (q0 + row)*256 + wid*64 + fr;
#pragma unroll
      for (int j = 0; j < 4; ++j)
        op[j*16] = f2b((acc[qm][j][r] - mu) * rs * gv4[j] + bv4[j]);
    }
}

// --------------------------- prep / elementwise ----------------------------

// Fused transpose of wq/wk/wv (split, into concat B[768][256]) and w0
// (non-split). z==3 block(0,0) also builds the 768-entry concat bias.
__global__ __launch_bounds__(256)
void k_transpose_qkv0(const float* __restrict__ wq, const float* __restrict__ wk,
                      const float* __restrict__ wv, const float* __restrict__ w0,
                      u16* __restrict__ catT_h, u16* __restrict__ catT_l,
                      u16* __restrict__ w0T,
                      const float* __restrict__ bq, const float* __restrict__ bk,
                      const float* __restrict__ bv, float* __restrict__ catBias) {
  __shared__ float t[32][33];
  const int z = blockIdx.z;
  const float* in = (z == 0) ? wq : (z == 1) ? wk : (z == 2) ? wv : w0;
  const int c0 = blockIdx.x * 32, r0 = blockIdx.y * 32;
  const int tx = threadIdx.x, ty = threadIdx.y;
#pragma unroll
  for (int i = 0; i < 4; ++i)
    t[ty + i*8][tx] = in[(long)(r0 + ty + i*8) * 256 + c0 + tx];
  __syncthreads();
#pragma unroll
  for (int i = 0; i < 4; ++i) {
    const float f = t[tx][ty + i*8];
    const u16 hb = f2b(f);
    if (z < 3) {
      const long o = (long)(z*256 + c0 + ty + i*8) * 256 + r0 + tx;
      catT_h[o] = hb;
      catT_l[o] = f2b(f - b2f(hb));
    } else {
      w0T[(long)(c0 + ty + i*8) * 256 + r0 + tx] = hb;
    }
  }
  if (z == 3 && blockIdx.x == 0 && blockIdx.y == 0) {
    const int t0 = ty * 32 + tx;   // 0..255
    catBias[t0] = bq[t0];
    catBias[256 + t0] = bk[t0];
    catBias[512 + t0] = bv[t0];
  }
}

__global__ __launch_bounds__(256)
void k_transpose_f32ns(const float* __restrict__ in, u16* __restrict__ hi, int R, int C) {
  __shared__ float t[32][33];
  const int c0 = blockIdx.x * 32, r0 = blockIdx.y * 32;
  const int tx = threadIdx.x, ty = threadIdx.y;
#pragma unroll
  for (int i = 0; i < 4; ++i)
    t[ty + i*8][tx] = in[(long)(r0 + ty + i*8) * C + c0 + tx];
  __syncthreads();
#pragma unroll
  for (int i = 0; i < 4; ++i)
    hi[(long)(c0 + ty + i*8) * R + r0 + tx] = f2b(t[tx][ty + i*8]);
}

__global__ __launch_bounds__(256)
void k_transpose_bf16(const u16* __restrict__ in, u16* __restrict__ out,
                      int R, int C, long sIn, long sOut) {
  __shared__ u16 t[32][34];
  const int z = blockIdx.z;
  const u16* ib = in + (long)z * sIn;
  u16* ob = out + (long)z * sOut;
  const int c0 = blockIdx.x * 32, r0 = blockIdx.y * 32;
  const int tx = threadIdx.x, ty = threadIdx.y;
#pragma unroll
  for (int i = 0; i < 4; ++i)
    t[ty + i*8][tx] = ib[(long)(r0 + ty + i*8) * C + c0 + tx];
  __syncthreads();
#pragma unroll
  for (int i = 0; i < 4; ++i)
    ob[(long)(c0 + ty + i*8) * R + r0 + tx] = t[tx][ty + i*8];
}

// h2 = leaky_relu(LN(h)) over 2048-wide rows (one block per row), in-place OK
__global__ __launch_bounds__(256)
void k_ln_leaky(const u16* __restrict__ h, const float* __restrict__ g,
                const float* __restrict__ b, u16* __restrict__ out) {
  const long row = blockIdx.x;
  const int tid = threadIdx.x;
  const int lane = tid & 63, wid = tid >> 6;
  const u16x8 hv = *(const u16x8*)(h + row * 2048 + tid * 8);
  float f[8];
  float s = 0.f, q = 0.f;
#pragma unroll
  for (int j = 0; j < 8; ++j) { f[j] = b2f(hv[j]); s += f[j]; q += f[j] * f[j]; }
  s = wave_sum(s); q = wave_sum(q);
  __shared__ float rs_[4], rq_[4];
  if (lane == 0) { rs_[wid] = s; rq_[wid] = q; }
  __syncthreads();
  s = rs_[0] + rs_[1] + rs_[2] + rs_[3];
  q = rq_[0] + rq_[1] + rq_[2] + rq_[3];
  const float mu = s * (1.f / 2048.f);
  const float var = q * (1.f / 2048.f) - mu * mu;
  const float rsq = rsqrtf(var + 1e-5f);
  const float4 g0 = *(const float4*)(g + tid * 8);
  const float4 g1 = *(const float4*)(g + tid * 8 + 4);
  const float4 b0 = *(const float4*)(b + tid * 8);
  const float4 b1 = *(const float4*)(b + tid * 8 + 4);
  const float gg[8] = {g0.x, g0.y, g0.z, g0.w, g1.x, g1.y, g1.z, g1.w};
  const float bb[8] = {b0.x, b0.y, b0.z, b0.w, b1.x, b1.y, b1.z, b1.w};
  u16x8 o;
#pragma unroll
  for (int j = 0; j < 8; ++j) {
    float y = (f[j] - mu) * rsq * gg[j] + bb[j];
    y = y > 0.f ? y : 0.01f * y;
    o[j] = f2b(y);
  }
  *(u16x8*)(out + row * 2048 + tid * 8) = o;
}

// out = LN(leaky_relu(logits + e)) -> fp32.  e is bf16.
__global__ __launch_bounds__(256)
void k_final(const float* __restrict__ lg, const u16* __restrict__ e,
             const float* __restrict__ g, const float* __restrict__ b,
             float* __restrict__ out) {
  const long row = (long)blockIdx.x * 4 + (threadIdx.x >> 6);
  const int lane = threadIdx.x & 63;
  const long base = row * 256 + lane * 4;
  const float4 lv = *(const float4*)(lg + base);
  const u16x4 ev = *(const u16x4*)(e + base);
  float t[4] = {lv.x + b2f(ev[0]), lv.y + b2f(ev[1]), lv.z + b2f(ev[2]), lv.w + b2f(ev[3])};
#pragma unroll
  for (int j = 0; j < 4; ++j) t[j] = t[j] > 0.f ? t[j] : 0.01f * t[j];
  float s = t[0] + t[1] + t[2] + t[3];
  float q = t[0]*t[0] + t[1]*t[1] + t[2]*t[2] + t[3]*t[3];
  s = wave_sum(s); q = wave_sum(q);
  const float mu = s * (1.f / 256.f);
  const float var = q * (1.f / 256.f) - mu * mu;
  const float rs = rsqrtf(var + 1e-5f);
  const float4 gv = *(const float4*)(g + lane * 4);
  const float4 bv = *(const float4*)(b + lane * 4);
  float4 o;
  o.x = (t[0] - mu) * rs * gv.x + bv.x;
  o.y = (t[1] - mu) * rs * gv.y + bv.y;
  o.z = (t[2] - mu) * rs * gv.z + bv.z;
  o.w = (t[3] - mu) * rs * gv.w + bv.w;
  *(float4*)(out + base) = o;
}

// ---------------------------------------------------------------------------

extern "C" void kernel_launch(void* const* d_in, const int* in_sizes, int n_in,
                              void* d_out, int out_size, void* d_ws, size_t ws_size,
                              hipStream_t stream) {
  const float* x   = (const float*)d_in[0];
  const float* wq  = (const float*)d_in[1];
  const float* bq  = (const float*)d_in[2];
  const float* wk  = (const float*)d_in[3];
  const float* bk  = (const float*)d_in[4];
  const float* wv  = (const float*)d_in[5];
  const float* bv_ = (const float*)d_in[6];
  const float* w0  = (const float*)d_in[7];
  const float* b0  = (const float*)d_in[8];
  const float* w1  = (const float*)d_in[9];
  const float* b1  = (const float*)d_in[10];
  const float* lmg = (const float*)d_in[11];
  const float* lmb = (const float*)d_in[12];
  const float* w2  = (const float*)d_in[13];
  const float* b2  = (const float*)d_in[14];
  const float* l1g = (const float*)d_in[15];
  const float* l1b = (const float*)d_in[16];
  const float* l2g = (const float*)d_in[17];
  const float* l2b = (const float*)d_in[18];

  char* ws = (char*)d_ws;
  float* out = (float*)d_out;

  // ws layout; peak ~106.9 MiB.
  u16* q16    = (u16*)(ws + 0);            // fp16 [4][4096][256]
  u16* k16    = (u16*)(ws + 16777216);
  u16* vT     = (u16*)(ws + 33554432);
  u16* v_b    = (u16*)(ws + 58720256);     // dead after transpose
  u16* ln1    = (u16*)(ws + 75497472);
  u16* e_b    = (u16*)(ws + 83886080);
  float* logits = (float*)(ws + 92274688); // 16 MiB, ends 109051904
  u16* h_b    = (u16*)(ws + 0);            // 64 MiB over dead q16/k16/vT/v_b
  u16* catT_h = (u16*)(ws + 109051904);    // [768][256] bf16-hi of f32 weights
  u16* catT_l = (u16*)(ws + 109445120);
  u16* w0T    = (u16*)(ws + 109838336);
  u16* w1T    = (u16*)(ws + 109969408);
  u16* w2T    = (u16*)(ws + 111017984);
  float* catBias = (float*)(ws + 112066560); // 768 f32, ends 112069632

  const dim3 t256(256);
  const dim3 tr(32, 8);

  // prep: fused transpose wq/wk/wv(+concat bias)/w0; w1; w2
  k_transpose_qkv0<<<dim3(8, 8, 4), tr, 0, stream>>>(
      wq, wk, wv, w0, catT_h, catT_l, w0T, bq, bk, bv_, catBias);
  k_transpose_f32ns<<<dim3(64, 8), tr, 0, stream>>>(w1, w1T, 256, 2048);
  k_transpose_f32ns<<<dim3(8, 64), tr, 0, stream>>>(w2, w2T, 2048, 256);

  // fused QKV projection: f32 x staged directly, converted in-kernel
  k_gemm_qkv<<<dim3(6, 128), t256, 0, stream>>>(
      x, catT_h, catT_l, catBias, q16, k16, v_b);
  k_transpose_bf16<<<dim3(8, 128, 4), tr, 0, stream>>>(v_b, vT, 4096, 256, 1048576, 1048576);

  // fused flash attention + LN(x+attn) epilogue -> ln1
  k_flash<<<dim3(128, 4), t256, 0, stream>>>(q16, k16, vT, x, l1g, l1b, ln1);

  // e = ln1 @ w0 + b0 (bf16)
  k_gemm_bt<false, 1><<<dim3(2, 128), t256, 0, stream>>>(
      ln1, nullptr, 256, w0T, nullptr, 256, b0, nullptr, e_b, nullptr, 256, 256);
  // h = e @ w1 + b1 (bf16, overlays dead q/k/v region)
  k_gemm_bt<false, 1><<<dim3(16, 128), t256, 0, stream>>>(
      e_b, nullptr, 256, w1T, nullptr, 256, b1, nullptr, h_b, nullptr, 2048, 256);
  // h2 = leaky(LN(h)) in place
  k_ln_leaky<<<16384, t256, 0, stream>>>(h_b, lmg, lmb, h_b);
  // logits = h2 @ w2 + b2 (f32)
  k_gemm_bt<false, 0><<<dim3(2, 128), t256, 0, stream>>>(
      h_b, nullptr, 2048, w2T, nullptr, 2048, b2, logits, nullptr, nullptr, 256, 2048);
  k_final<<<4096, t256, 0, stream>>>(logits, e_b, l2g, l2b, out);
}

// Round 23
// 319.693 us; speedup vs baseline: 1.0771x; 1.0452x over previous
//
#include <hip/hip_runtime.h>

typedef unsigned short u16;
typedef unsigned int   u32;
typedef u16   u16x4 __attribute__((ext_vector_type(4)));
typedef u16   u16x8 __attribute__((ext_vector_type(8)));
typedef short s16x8 __attribute__((ext_vector_type(8)));
typedef u32   u32x4 __attribute__((ext_vector_type(4)));
typedef float f32x4 __attribute__((ext_vector_type(4)));
typedef _Float16 f16x8 __attribute__((ext_vector_type(8)));

__device__ __forceinline__ u16 f2b(float f) {
  u32 u = __builtin_bit_cast(u32, f);
  u32 r = (u + 0x7fffu + ((u >> 16) & 1u)) >> 16;
  return (u16)r;
}
__device__ __forceinline__ float b2f(u16 h) {
  return __builtin_bit_cast(float, (u32)h << 16);
}
__device__ __forceinline__ u16 f2h(float f) {
  _Float16 h = (_Float16)f;           // v_cvt_f16_f32 (RNE)
  return __builtin_bit_cast(u16, h);
}
__device__ __forceinline__ u32 cvtpk(float a, float b) {  // low16=bf16(a), high16=bf16(b)
  u32 r; asm("v_cvt_pk_bf16_f32 %0, %1, %2" : "=v"(r) : "v"(a), "v"(b)); return r;
}

__device__ __forceinline__ void async16(void* l, const void* g) {
  __builtin_amdgcn_global_load_lds((const __attribute__((address_space(1))) u32*)g,
                                   (__attribute__((address_space(3))) u32*)l, 16, 0, 0);
}

__device__ __forceinline__ float wave_sum(float v) {
#pragma unroll
  for (int m = 32; m; m >>= 1) v += __shfl_xor(v, m, 64);
  return v;
}

// ---------------------------------------------------------------------------
// GEMM:  C[M,N] = A[M,K] @ B[N,K]^T (+bias[N])
// OMODE: 0=f32, 1=bf16
// ---------------------------------------------------------------------------
constexpr int BM = 128, BN = 128, BK = 64;

template<bool SPLIT, int OMODE>
__global__ __launch_bounds__(256)
void k_gemm_bt(const u16* __restrict__ Ah, const u16* __restrict__ Al, long lda,
               const u16* __restrict__ Bh, const u16* __restrict__ Bl, long ldb,
               const float* __restrict__ bias,
               float* __restrict__ Cf, u16* __restrict__ Cb, u16* __restrict__ Cl,
               long ldc, int K)
{
  __shared__ u16 lds[(SPLIT ? 4 : 2) * BM * BK];
  const int tid = threadIdx.x;
  const long arow0 = (long)blockIdx.y * BM;
  const long bcol0 = (long)blockIdx.x * BN;

  long offA[4], offB[4];
#pragma unroll
  for (int r = 0; r < 4; ++r) {
    const int off = r * 4096 + tid * 16;
    const int row = off >> 7;
    const int colb = off & 127;
    offA[r] = (arow0 + row) * lda + (colb >> 1);
    offB[r] = (bcol0 + row) * ldb + (colb >> 1);
  }

  const int lane = tid & 63;
  const int wid = tid >> 6;
  const int wr = (wid >> 1) * 64;
  const int wc = (wid & 1) * 64;
  const int fr = lane & 15;
  const int fk = (lane >> 4) * 8;

  f32x4 acc[4][4] = {};

  for (int k0 = 0; k0 < K; k0 += BK) {
#pragma unroll
    for (int r = 0; r < 4; ++r) {
      const int loff = (r * 4096 + tid * 16) >> 1;
      async16(&lds[loff],           Ah + offA[r] + k0);
      async16(&lds[BM*BK + loff],   Bh + offB[r] + k0);
      if constexpr (SPLIT) {
        async16(&lds[2*BM*BK + loff], Al + offA[r] + k0);
        async16(&lds[3*BM*BK + loff], Bl + offB[r] + k0);
      }
    }
    __syncthreads();
#pragma unroll
    for (int kk = 0; kk < BK; kk += 32) {
      s16x8 a[4], b[4];
#pragma unroll
      for (int m = 0; m < 4; ++m)
        a[m] = *(const s16x8*)&lds[(wr + m*16 + fr) * BK + kk + fk];
#pragma unroll
      for (int n = 0; n < 4; ++n)
        b[n] = *(const s16x8*)&lds[BM*BK + (wc + n*16 + fr) * BK + kk + fk];
#pragma unroll
      for (int m = 0; m < 4; ++m)
#pragma unroll
        for (int n = 0; n < 4; ++n)
          acc[m][n] = __builtin_amdgcn_mfma_f32_16x16x32_bf16(a[m], b[n], acc[m][n], 0, 0, 0);
      if constexpr (SPLIT) {
        s16x8 al[4], bl[4];
#pragma unroll
        for (int m = 0; m < 4; ++m)
          al[m] = *(const s16x8*)&lds[2*BM*BK + (wr + m*16 + fr) * BK + kk + fk];
#pragma unroll
        for (int n = 0; n < 4; ++n)
          bl[n] = *(const s16x8*)&lds[3*BM*BK + (wc + n*16 + fr) * BK + kk + fk];
#pragma unroll
        for (int m = 0; m < 4; ++m)
#pragma unroll
          for (int n = 0; n < 4; ++n) {
            acc[m][n] = __builtin_amdgcn_mfma_f32_16x16x32_bf16(a[m], bl[n], acc[m][n], 0, 0, 0);
            acc[m][n] = __builtin_amdgcn_mfma_f32_16x16x32_bf16(al[m], b[n], acc[m][n], 0, 0, 0);
          }
      }
    }
    __syncthreads();
  }

  float bv[4];
#pragma unroll
  for (int n = 0; n < 4; ++n) {
    const long gcol = bcol0 + wc + n*16 + fr;
    bv[n] = bias ? bias[gcol] : 0.f;
  }

#pragma unroll
  for (int m = 0; m < 4; ++m) {
#pragma unroll
    for (int reg = 0; reg < 4; ++reg) {
      const long grow = arow0 + wr + m*16 + (lane >> 4) * 4 + reg;
      const long ro = grow * ldc;
#pragma unroll
      for (int n = 0; n < 4; ++n) {
        const long gcol = bcol0 + wc + n*16 + fr;
        const float val = acc[m][n][reg] + bv[n];
        if constexpr (OMODE == 0) {
          Cf[ro + gcol] = val;
        } else {
          Cb[ro + gcol] = f2b(val);
        }
      }
    }
  }
}

// ---------------------------------------------------------------------------
// w2 GEMM with split-K (grid.z = 2): z computes K in [z*1024, z*1024+1024)
// into plane C0 (z=0, +bias) or C1 (z=1, no bias).
// A = h [16384][2048] bf16, B = w2T [256][2048] bf16.
// ---------------------------------------------------------------------------
__global__ __launch_bounds__(256)
void k_gemm_w2sk(const u16* __restrict__ Ah, const u16* __restrict__ Bh,
                 const float* __restrict__ bias,
                 float* __restrict__ C0, float* __restrict__ C1)
{
  __shared__ u16 lds[2 * BM * BK];
  const int tid = threadIdx.x;
  const long arow0 = (long)blockIdx.y * BM;
  const long bcol0 = (long)blockIdx.x * BN;
  const int zs = blockIdx.z;
  const int kbase = zs * 1024;
  float* Cz = zs ? C1 : C0;

  long offA[4], offB[4];
#pragma unroll
  for (int r = 0; r < 4; ++r) {
    const int off = r * 4096 + tid * 16;
    const int row = off >> 7;
    const int colb = off & 127;
    offA[r] = (arow0 + row) * 2048 + (colb >> 1) + kbase;
    offB[r] = (bcol0 + row) * 2048 + (colb >> 1) + kbase;
  }

  const int lane = tid & 63;
  const int wid = tid >> 6;
  const int wr = (wid >> 1) * 64;
  const int wc = (wid & 1) * 64;
  const int fr = lane & 15;
  const int fk = (lane >> 4) * 8;

  f32x4 acc[4][4] = {};

  for (int k0 = 0; k0 < 1024; k0 += BK) {
#pragma unroll
    for (int r = 0; r < 4; ++r) {
      const int loff = (r * 4096 + tid * 16) >> 1;
      async16(&lds[loff],         Ah + offA[r] + k0);
      async16(&lds[BM*BK + loff], Bh + offB[r] + k0);
    }
    __syncthreads();
#pragma unroll
    for (int kk = 0; kk < BK; kk += 32) {
      s16x8 a[4], b[4];
#pragma unroll
      for (int m = 0; m < 4; ++m)
        a[m] = *(const s16x8*)&lds[(wr + m*16 + fr) * BK + kk + fk];
#pragma unroll
      for (int n = 0; n < 4; ++n)
        b[n] = *(const s16x8*)&lds[BM*BK + (wc + n*16 + fr) * BK + kk + fk];
#pragma unroll
      for (int m = 0; m < 4; ++m)
#pragma unroll
        for (int n = 0; n < 4; ++n)
          acc[m][n] = __builtin_amdgcn_mfma_f32_16x16x32_bf16(a[m], b[n], acc[m][n], 0, 0, 0);
    }
    __syncthreads();
  }

  float bv[4];
#pragma unroll
  for (int n = 0; n < 4; ++n)
    bv[n] = (zs == 0) ? bias[bcol0 + wc + n*16 + fr] : 0.f;

#pragma unroll
  for (int m = 0; m < 4; ++m) {
#pragma unroll
    for (int reg = 0; reg < 4; ++reg) {
      const long grow = arow0 + wr + m*16 + (lane >> 4) * 4 + reg;
      const long ro = grow * 256;
#pragma unroll
      for (int n = 0; n < 4; ++n) {
        const long gcol = bcol0 + wc + n*16 + fr;
        Cz[ro + gcol] = acc[m][n][reg] + bv[n];
      }
    }
  }
}

// ---------------------------------------------------------------------------
// Fused QKV GEMM with f32 A (x) staged directly; A converted to bf16 hi/lo
// on the fly via v_cvt_pk_bf16_f32. 3-product split numerics.
// ---------------------------------------------------------------------------
__global__ __launch_bounds__(256)
void k_gemm_qkv(const float* __restrict__ Af,   // x [16384][256] f32
                const u16* __restrict__ Bh, const u16* __restrict__ Bl,
                const float* __restrict__ bias, // catBias[768]
                u16* __restrict__ Cq, u16* __restrict__ Ck, u16* __restrict__ Cv)
{
  __shared__ float ldsA[BM * BK];   // 32KB
  __shared__ u16 ldsBh[BN * BK];    // 16KB
  __shared__ u16 ldsBl[BN * BK];    // 16KB
  const int tid = threadIdx.x;
  const long arow0 = (long)blockIdx.y * BM;
  const long bcol0 = (long)blockIdx.x * BN;

  long offA[8];
#pragma unroll
  for (int r = 0; r < 8; ++r) {
    const int off = r * 4096 + tid * 16;   // byte in 32KB A tile
    const int row = off >> 8;              // 256B per row (64 f32)
    const int colb = off & 255;
    offA[r] = (arow0 + row) * 256 + (colb >> 2);
  }
  long offB[4];
#pragma unroll
  for (int r = 0; r < 4; ++r) {
    const int off = r * 4096 + tid * 16;
    const int row = off >> 7;
    const int colb = off & 127;
    offB[r] = (bcol0 + row) * 256 + (colb >> 1);
  }

  const int lane = tid & 63;
  const int wid = tid >> 6;
  const int wr = (wid >> 1) * 64;
  const int wc = (wid & 1) * 64;
  const int fr = lane & 15;
  const int fk = (lane >> 4) * 8;

  f32x4 acc[4][4] = {};

  for (int k0 = 0; k0 < 256; k0 += BK) {
#pragma unroll
    for (int r = 0; r < 8; ++r)
      async16((char*)ldsA + r*4096 + tid*16, Af + offA[r] + k0);
#pragma unroll
    for (int r = 0; r < 4; ++r) {
      const int loff = (r * 4096 + tid * 16) >> 1;
      async16(&ldsBh[loff], Bh + offB[r] + k0);
      async16(&ldsBl[loff], Bl + offB[r] + k0);
    }
    __syncthreads();
#pragma unroll
    for (int kk = 0; kk < BK; kk += 32) {
      s16x8 a[4], al[4];
#pragma unroll
      for (int m = 0; m < 4; ++m) {
        const float* ap = &ldsA[(wr + m*16 + fr) * BK + kk + fk];
        const float4 v0 = *(const float4*)ap;
        const float4 v1 = *(const float4*)(ap + 4);
        u32x4 H, L;
        H[0] = cvtpk(v0.x, v0.y); H[1] = cvtpk(v0.z, v0.w);
        H[2] = cvtpk(v1.x, v1.y); H[3] = cvtpk(v1.z, v1.w);
        L[0] = cvtpk(v0.x - __builtin_bit_cast(float, H[0] << 16),
                     v0.y - __builtin_bit_cast(float, H[0] & 0xffff0000u));
        L[1] = cvtpk(v0.z - __builtin_bit_cast(float, H[1] << 16),
                     v0.w - __builtin_bit_cast(float, H[1] & 0xffff0000u));
        L[2] = cvtpk(v1.x - __builtin_bit_cast(float, H[2] << 16),
                     v1.y - __builtin_bit_cast(float, H[2] & 0xffff0000u));
        L[3] = cvtpk(v1.z - __builtin_bit_cast(float, H[3] << 16),
                     v1.w - __builtin_bit_cast(float, H[3] & 0xffff0000u));
        a[m]  = __builtin_bit_cast(s16x8, H);
        al[m] = __builtin_bit_cast(s16x8, L);
      }
      s16x8 b[4], bl[4];
#pragma unroll
      for (int n = 0; n < 4; ++n) {
        b[n]  = *(const s16x8*)&ldsBh[(wc + n*16 + fr) * BK + kk + fk];
        bl[n] = *(const s16x8*)&ldsBl[(wc + n*16 + fr) * BK + kk + fk];
      }
#pragma unroll
      for (int m = 0; m < 4; ++m)
#pragma unroll
        for (int n = 0; n < 4; ++n) {
          acc[m][n] = __builtin_amdgcn_mfma_f32_16x16x32_bf16(a[m],  b[n],  acc[m][n], 0, 0, 0);
          acc[m][n] = __builtin_amdgcn_mfma_f32_16x16x32_bf16(a[m],  bl[n], acc[m][n], 0, 0, 0);
          acc[m][n] = __builtin_amdgcn_mfma_f32_16x16x32_bf16(al[m], b[n],  acc[m][n], 0, 0, 0);
        }
    }
    __syncthreads();
  }

  float bv[4];
#pragma unroll
  for (int n = 0; n < 4; ++n)
    bv[n] = bias[bcol0 + wc + n*16 + fr];

  const int band = (int)(bcol0 >> 8);   // 0=q,1=k,2=v (block-uniform)
  u16* dst = (band == 0) ? Cq : (band == 1) ? Ck : Cv;

#pragma unroll
  for (int m = 0; m < 4; ++m) {
#pragma unroll
    for (int reg = 0; reg < 4; ++reg) {
      const long grow = arow0 + wr + m*16 + (lane >> 4) * 4 + reg;
#pragma unroll
      for (int n = 0; n < 4; ++n) {
        const long lc = bcol0 - (long)band*256 + wc + n*16 + fr;
        const float val = acc[m][n][reg] + bv[n];
        dst[grow * 256 + lc] = (band < 2) ? f2h(val) : f2b(val);
      }
    }
  }
}

// ---------------------------------------------------------------------------
// Flash attention v9: KSTEP=64, fp16 Q/K single product, double-buffered
// 32KB K tiles, fused LN(x + attn) epilogue writing ln1 bf16 directly.
// ---------------------------------------------------------------------------
__global__ __launch_bounds__(256)
void k_flash(const u16* __restrict__ q16, const u16* __restrict__ k16,
             const u16* __restrict__ vt,   // [256][4096] per batch (V^T), bf16
             const float* __restrict__ x,  // [4][4096][256] f32
             const float* __restrict__ g, const float* __restrict__ b,
             u16* __restrict__ ln1)        // [4][4096][256] bf16
{
  __shared__ u16 lkh[2][64*256];  // 64KB: K fp16 tiles, 512B rows, swizzled
  __shared__ float lS[32*68];     // S tile fp32, padded rows (272B); reused for LN
  __shared__ u16 lP[32*72];       // P bf16, rows padded to 144B
  __shared__ float lm[32], ll[32], lsc[32];

  const int tid = threadIdx.x;
  const int lane = tid & 63, wid = tid >> 6;
  const long bo = (long)blockIdx.y * 1048576;   // batch offset (elements)
  const long q0 = (long)blockIdx.x * 32;

  const int fr  = lane & 15;
  const int hi2 = lane >> 4;
  const int fk  = hi2 * 8;
  const int qh_sel = wid >> 1;
  const int kh_sel = wid & 1;

  // Q fragments in registers (fp16)
  f16x8 qf[8];
  {
    const u16* qp = q16 + bo + (q0 + qh_sel*16 + fr) * 256;
#pragma unroll
    for (int c = 0; c < 8; ++c)
      qf[c] = *(const f16x8*)(qp + c*32 + fk);
  }

  if (tid < 32) { lm[tid] = -1e30f; ll[tid] = 0.f; }
  f32x4 acc[2][4] = {};

  const char* kp = (const char*)(k16 + bo);
  const u16* vbase = vt + bo;

  auto STAGE = [&](int k0s, int bsel) {
#pragma unroll
    for (int r = 0; r < 8; ++r) {
      const int L = r*4096 + tid*16;          // byte offset in 32KB tile
      const int row = L >> 9;                 // 0..63
      const int colb = L & 511;
      const long gb = (long)(k0s + row)*512 + (colb ^ ((row & 7) << 4));
      async16((char*)lkh[bsel] + L, kp + gb);
    }
  };

  STAGE(0, 0);
  __syncthreads();   // prologue: tile 0 staged (implicit vmcnt drain, once)

  int cur = 0;
  for (int k0 = 0; k0 < 4096; k0 += 64) {
    // --- V prefetch into regs: 2 k-slices x 4 d-tiles ---
    s16x8 vb[2][4];
#pragma unroll
    for (int ks = 0; ks < 2; ++ks)
#pragma unroll
      for (int j = 0; j < 4; ++j)
        vb[ks][j] = *(const s16x8*)(vbase + (long)(wid*64 + j*16 + fr)*4096 + k0 + ks*32 + fk);

    // --- stage next K tile into the other buffer ---
    if (k0 + 64 < 4096) STAGE(k0 + 64, cur ^ 1);

    // --- QK^T: wave covers 16q x 32k via two chains ---
    f32x4 s0 = {}, s1 = {};
    const int kc0 = kh_sel*32 + fr;           // chain0 k-row; chain1 = +16
    const int swz = (kc0 & 7) << 4;           // (kc0+16)&7 == kc0&7
#pragma unroll
    for (int c = 0; c < 8; ++c) {
      const int o = (c*64 + hi2*16) ^ swz;
      const f16x8 b0 = *(const f16x8*)((const char*)lkh[cur] + kc0*512 + o);
      const f16x8 b1 = *(const f16x8*)((const char*)lkh[cur] + (kc0 + 16)*512 + o);
      s0 = __builtin_amdgcn_mfma_f32_16x16x32_f16(qf[c], b0, s0, 0, 0, 0);
      s1 = __builtin_amdgcn_mfma_f32_16x16x32_f16(qf[c], b1, s1, 0, 0, 0);
    }
#pragma unroll
    for (int r = 0; r < 4; ++r) {
      const int srow = (qh_sel*16 + hi2*4 + r) * 68;
      lS[srow + kh_sel*32 + fr]      = s0[r];
      lS[srow + kh_sel*32 + 16 + fr] = s1[r];
    }
    __syncthreads();   // S visible (also drains next-tile stage, under QKT)

    // --- online softmax: thread t owns row t>>3, cols (t&7)*8 .. +8 ---
    {
      const int sr = tid >> 3;
      const int sc = (tid & 7) * 8;
      const float4 sv0 = *(const float4*)&lS[sr*68 + sc];
      const float4 sv1 = *(const float4*)&lS[sr*68 + sc + 4];
      float tmx = fmaxf(fmaxf(fmaxf(sv0.x, sv0.y), fmaxf(sv0.z, sv0.w)),
                        fmaxf(fmaxf(sv1.x, sv1.y), fmaxf(sv1.z, sv1.w)));
#pragma unroll
      for (int m = 1; m < 8; m <<= 1) tmx = fmaxf(tmx, __shfl_xor(tmx, m, 64));
      const float mold = lm[sr];
      const float mnew = fmaxf(mold, tmx);
      const float p0 = __expf(sv0.x - mnew), p1 = __expf(sv0.y - mnew);
      const float p2 = __expf(sv0.z - mnew), p3 = __expf(sv0.w - mnew);
      const float p4 = __expf(sv1.x - mnew), p5 = __expf(sv1.y - mnew);
      const float p6 = __expf(sv1.z - mnew), p7 = __expf(sv1.w - mnew);
      float ps = ((p0 + p1) + (p2 + p3)) + ((p4 + p5) + (p6 + p7));
#pragma unroll
      for (int m = 1; m < 8; m <<= 1) ps += __shfl_xor(ps, m, 64);
      const float scale = __expf(mold - mnew);
      if ((tid & 7) == 0) {
        lm[sr] = mnew;
        ll[sr] = ll[sr] * scale + ps;
        lsc[sr] = scale;
      }
      u16x8 pb;
      pb[0]=f2b(p0); pb[1]=f2b(p1); pb[2]=f2b(p2); pb[3]=f2b(p3);
      pb[4]=f2b(p4); pb[5]=f2b(p5); pb[6]=f2b(p6); pb[7]=f2b(p7);
      *(u16x8*)&lP[sr*72 + sc] = pb;
    }
    __syncthreads();   // P, lsc, ll visible

    // --- PV: rescale acc, then acc += P @ V over 2 k-slices ---
#pragma unroll
    for (int qm = 0; qm < 2; ++qm)
#pragma unroll
      for (int r = 0; r < 4; ++r) {
        const float s = lsc[qm*16 + hi2*4 + r];
#pragma unroll
        for (int j = 0; j < 4; ++j) acc[qm][j][r] *= s;
      }
#pragma unroll
    for (int qm = 0; qm < 2; ++qm)
#pragma unroll
      for (int ks = 0; ks < 2; ++ks) {
        const s16x8 pa = *(const s16x8*)&lP[(qm*16 + fr)*72 + ks*32 + fk];
#pragma unroll
        for (int j = 0; j < 4; ++j)
          acc[qm][j] = __builtin_amdgcn_mfma_f32_16x16x32_bf16(pa, vb[ks][j], acc[qm][j], 0, 0, 0);
      }
    cur ^= 1;
  }

  // ---- fused epilogue: t = x + attn/l;  ln1 = LN(t) ----
  __syncthreads();   // all lS/lP reads done; reuse lS for LN partials
  float gv4[4], bv4[4];
#pragma unroll
  for (int j = 0; j < 4; ++j) {
    gv4[j] = g[wid*64 + j*16 + fr];
    bv4[j] = b[wid*64 + j*16 + fr];
  }
  const float* xb = x + bo + q0*256;
#pragma unroll
  for (int qm = 0; qm < 2; ++qm)
#pragma unroll
    for (int r = 0; r < 4; ++r) {
      const int row = qm*16 + hi2*4 + r;
      const float inv = 1.0f / ll[row];
      const float* xp = xb + (long)row*256 + wid*64 + fr;
      float s = 0.f, qq = 0.f;
#pragma unroll
      for (int j = 0; j < 4; ++j) {
        const float t = acc[qm][j][r] * inv + xp[j*16];
        acc[qm][j][r] = t;
        s += t; qq += t*t;
      }
#pragma unroll
      for (int m = 1; m < 16; m <<= 1) {
        s  += __shfl_xor(s, m, 64);
        qq += __shfl_xor(qq, m, 64);
      }
      if (fr == 0) { lS[row*4 + wid] = s; lS[128 + row*4 + wid] = qq; }
    }
  __syncthreads();
#pragma unroll
  for (int qm = 0; qm < 2; ++qm)
#pragma unroll
    for (int r = 0; r < 4; ++r) {
      const int row = qm*16 + hi2*4 + r;
      const float s  = (lS[row*4+0] + lS[row*4+1]) + (lS[row*4+2] + lS[row*4+3]);
      const float qq = (lS[128+row*4+0] + lS[128+row*4+1]) + (lS[128+row*4+2] + lS[128+row*4+3]);
      const float mu = s * (1.f / 256.f);
      const float var = qq * (1.f / 256.f) - mu * mu;
      const float rs = rsqrtf(var + 1e-5f);
      u16* op = ln1 + bo + (q0 + row)*256 + wid*64 + fr;
#pragma unroll
      for (int j = 0; j < 4; ++j)
        op[j*16] = f2b((acc[qm][j][r] - mu) * rs * gv4[j] + bv4[j]);
    }
}

// --------------------------- prep / elementwise ----------------------------

// Fused transpose of wq/wk/wv (split, into concat B[768][256]) and w0
// (non-split). z==3 block(0,0) also builds the 768-entry concat bias.
__global__ __launch_bounds__(256)
void k_transpose_qkv0(const float* __restrict__ wq, const float* __restrict__ wk,
                      const float* __restrict__ wv, const float* __restrict__ w0,
                      u16* __restrict__ catT_h, u16* __restrict__ catT_l,
                      u16* __restrict__ w0T,
                      const float* __restrict__ bq, const float* __restrict__ bk,
                      const float* __restrict__ bv, float* __restrict__ catBias) {
  __shared__ float t[32][33];
  const int z = blockIdx.z;
  const float* in = (z == 0) ? wq : (z == 1) ? wk : (z == 2) ? wv : w0;
  const int c0 = blockIdx.x * 32, r0 = blockIdx.y * 32;
  const int tx = threadIdx.x, ty = threadIdx.y;
#pragma unroll
  for (int i = 0; i < 4; ++i)
    t[ty + i*8][tx] = in[(long)(r0 + ty + i*8) * 256 + c0 + tx];
  __syncthreads();
#pragma unroll
  for (int i = 0; i < 4; ++i) {
    const float f = t[tx][ty + i*8];
    const u16 hb = f2b(f);
    if (z < 3) {
      const long o = (long)(z*256 + c0 + ty + i*8) * 256 + r0 + tx;
      catT_h[o] = hb;
      catT_l[o] = f2b(f - b2f(hb));
    } else {
      w0T[(long)(c0 + ty + i*8) * 256 + r0 + tx] = hb;
    }
  }
  if (z == 3 && blockIdx.x == 0 && blockIdx.y == 0) {
    const int t0 = ty * 32 + tx;   // 0..255
    catBias[t0] = bq[t0];
    catBias[256 + t0] = bk[t0];
    catBias[512 + t0] = bv[t0];
  }
}

__global__ __launch_bounds__(256)
void k_transpose_f32ns(const float* __restrict__ in, u16* __restrict__ hi, int R, int C) {
  __shared__ float t[32][33];
  const int c0 = blockIdx.x * 32, r0 = blockIdx.y * 32;
  const int tx = threadIdx.x, ty = threadIdx.y;
#pragma unroll
  for (int i = 0; i < 4; ++i)
    t[ty + i*8][tx] = in[(long)(r0 + ty + i*8) * C + c0 + tx];
  __syncthreads();
#pragma unroll
  for (int i = 0; i < 4; ++i)
    hi[(long)(c0 + ty + i*8) * R + r0 + tx] = f2b(t[tx][ty + i*8]);
}

__global__ __launch_bounds__(256)
void k_transpose_bf16(const u16* __restrict__ in, u16* __restrict__ out,
                      int R, int C, long sIn, long sOut) {
  __shared__ u16 t[32][34];
  const int z = blockIdx.z;
  const u16* ib = in + (long)z * sIn;
  u16* ob = out + (long)z * sOut;
  const int c0 = blockIdx.x * 32, r0 = blockIdx.y * 32;
  const int tx = threadIdx.x, ty = threadIdx.y;
#pragma unroll
  for (int i = 0; i < 4; ++i)
    t[ty + i*8][tx] = ib[(long)(r0 + ty + i*8) * C + c0 + tx];
  __syncthreads();
#pragma unroll
  for (int i = 0; i < 4; ++i)
    ob[(long)(c0 + ty + i*8) * R + r0 + tx] = t[tx][ty + i*8];
}

// h2 = leaky_relu(LN(h)) over 2048-wide rows (one block per row), in-place OK
__global__ __launch_bounds__(256)
void k_ln_leaky(const u16* __restrict__ h, const float* __restrict__ g,
                const float* __restrict__ b, u16* __restrict__ out) {
  const long row = blockIdx.x;
  const int tid = threadIdx.x;
  const int lane = tid & 63, wid = tid >> 6;
  const u16x8 hv = *(const u16x8*)(h + row * 2048 + tid * 8);
  float f[8];
  float s = 0.f, q = 0.f;
#pragma unroll
  for (int j = 0; j < 8; ++j) { f[j] = b2f(hv[j]); s += f[j]; q += f[j] * f[j]; }
  s = wave_sum(s); q = wave_sum(q);
  __shared__ float rs_[4], rq_[4];
  if (lane == 0) { rs_[wid] = s; rq_[wid] = q; }
  __syncthreads();
  s = rs_[0] + rs_[1] + rs_[2] + rs_[3];
  q = rq_[0] + rq_[1] + rq_[2] + rq_[3];
  const float mu = s * (1.f / 2048.f);
  const float var = q * (1.f / 2048.f) - mu * mu;
  const float rsq = rsqrtf(var + 1e-5f);
  const float4 g0 = *(const float4*)(g + tid * 8);
  const float4 g1 = *(const float4*)(g + tid * 8 + 4);
  const float4 b0 = *(const float4*)(b + tid * 8);
  const float4 b1 = *(const float4*)(b + tid * 8 + 4);
  const float gg[8] = {g0.x, g0.y, g0.z, g0.w, g1.x, g1.y, g1.z, g1.w};
  const float bb[8] = {b0.x, b0.y, b0.z, b0.w, b1.x, b1.y, b1.z, b1.w};
  u16x8 o;
#pragma unroll
  for (int j = 0; j < 8; ++j) {
    float y = (f[j] - mu) * rsq * gg[j] + bb[j];
    y = y > 0.f ? y : 0.01f * y;
    o[j] = f2b(y);
  }
  *(u16x8*)(out + row * 2048 + tid * 8) = o;
}

// out = LN(leaky_relu(lg0 + lg1 + e)) -> fp32.  e is bf16; lg split-K planes.
__global__ __launch_bounds__(256)
void k_final(const float* __restrict__ lg0, const float* __restrict__ lg1,
             const u16* __restrict__ e,
             const float* __restrict__ g, const float* __restrict__ b,
             float* __restrict__ out) {
  const long row = (long)blockIdx.x * 4 + (threadIdx.x >> 6);
  const int lane = threadIdx.x & 63;
  const long base = row * 256 + lane * 4;
  const float4 l0 = *(const float4*)(lg0 + base);
  const float4 l1 = *(const float4*)(lg1 + base);
  const u16x4 ev = *(const u16x4*)(e + base);
  float t[4] = {l0.x + l1.x + b2f(ev[0]), l0.y + l1.y + b2f(ev[1]),
                l0.z + l1.z + b2f(ev[2]), l0.w + l1.w + b2f(ev[3])};
#pragma unroll
  for (int j = 0; j < 4; ++j) t[j] = t[j] > 0.f ? t[j] : 0.01f * t[j];
  float s = t[0] + t[1] + t[2] + t[3];
  float q = t[0]*t[0] + t[1]*t[1] + t[2]*t[2] + t[3]*t[3];
  s = wave_sum(s); q = wave_sum(q);
  const float mu = s * (1.f / 256.f);
  const float var = q * (1.f / 256.f) - mu * mu;
  const float rs = rsqrtf(var + 1e-5f);
  const float4 gv = *(const float4*)(g + lane * 4);
  const float4 bv = *(const float4*)(b + lane * 4);
  float4 o;
  o.x = (t[0] - mu) * rs * gv.x + bv.x;
  o.y = (t[1] - mu) * rs * gv.y + bv.y;
  o.z = (t[2] - mu) * rs * gv.z + bv.z;
  o.w = (t[3] - mu) * rs * gv.w + bv.w;
  *(float4*)(out + base) = o;
}

// ---------------------------------------------------------------------------

extern "C" void kernel_launch(void* const* d_in, const int* in_sizes, int n_in,
                              void* d_out, int out_size, void* d_ws, size_t ws_size,
                              hipStream_t stream) {
  const float* x   = (const float*)d_in[0];
  const float* wq  = (const float*)d_in[1];
  const float* bq  = (const float*)d_in[2];
  const float* wk  = (const float*)d_in[3];
  const float* bk  = (const float*)d_in[4];
  const float* wv  = (const float*)d_in[5];
  const float* bv_ = (const float*)d_in[6];
  const float* w0  = (const float*)d_in[7];
  const float* b0  = (const float*)d_in[8];
  const float* w1  = (const float*)d_in[9];
  const float* b1  = (const float*)d_in[10];
  const float* lmg = (const float*)d_in[11];
  const float* lmb = (const float*)d_in[12];
  const float* w2  = (const float*)d_in[13];
  const float* b2  = (const float*)d_in[14];
  const float* l1g = (const float*)d_in[15];
  const float* l1b = (const float*)d_in[16];
  const float* l2g = (const float*)d_in[17];
  const float* l2b = (const float*)d_in[18];

  char* ws = (char*)d_ws;
  float* out = (float*)d_out;

  // ws layout; peak ~122.9 MiB (logits2 appended; < proven 137 MiB budget).
  u16* q16    = (u16*)(ws + 0);            // fp16 [4][4096][256]
  u16* k16    = (u16*)(ws + 16777216);
  u16* vT     = (u16*)(ws + 33554432);
  u16* v_b    = (u16*)(ws + 58720256);     // dead after transpose
  u16* ln1    = (u16*)(ws + 75497472);
  u16* e_b    = (u16*)(ws + 83886080);
  float* logits = (float*)(ws + 92274688); // 16 MiB plane 0, ends 109051904
  u16* h_b    = (u16*)(ws + 0);            // 64 MiB over dead q16/k16/vT/v_b
  u16* catT_h = (u16*)(ws + 109051904);    // [768][256] bf16-hi of f32 weights
  u16* catT_l = (u16*)(ws + 109445120);
  u16* w0T    = (u16*)(ws + 109838336);
  u16* w1T    = (u16*)(ws + 109969408);
  u16* w2T    = (u16*)(ws + 111017984);
  float* catBias = (float*)(ws + 112066560); // 768 f32, ends 112069632
  float* logits2 = (float*)(ws + 112069888); // 16 MiB plane 1, ends 128847104

  const dim3 t256(256);
  const dim3 tr(32, 8);

  // prep: fused transpose wq/wk/wv(+concat bias)/w0; w1; w2
  k_transpose_qkv0<<<dim3(8, 8, 4), tr, 0, stream>>>(
      wq, wk, wv, w0, catT_h, catT_l, w0T, bq, bk, bv_, catBias);
  k_transpose_f32ns<<<dim3(64, 8), tr, 0, stream>>>(w1, w1T, 256, 2048);
  k_transpose_f32ns<<<dim3(8, 64), tr, 0, stream>>>(w2, w2T, 2048, 256);

  // fused QKV projection: f32 x staged directly, converted in-kernel
  k_gemm_qkv<<<dim3(6, 128), t256, 0, stream>>>(
      x, catT_h, catT_l, catBias, q16, k16, v_b);
  k_transpose_bf16<<<dim3(8, 128, 4), tr, 0, stream>>>(v_b, vT, 4096, 256, 1048576, 1048576);

  // fused flash attention + LN(x+attn) epilogue -> ln1
  k_flash<<<dim3(128, 4), t256, 0, stream>>>(q16, k16, vT, x, l1g, l1b, ln1);

  // e = ln1 @ w0 + b0 (bf16)
  k_gemm_bt<false, 1><<<dim3(2, 128), t256, 0, stream>>>(
      ln1, nullptr, 256, w0T, nullptr, 256, b0, nullptr, e_b, nullptr, 256, 256);
  // h = e @ w1 + b1 (bf16, overlays dead q/k/v region)
  k_gemm_bt<false, 1><<<dim3(16, 128), t256, 0, stream>>>(
      e_b, nullptr, 256, w1T, nullptr, 256, b1, nullptr, h_b, nullptr, 2048, 256);
  // h2 = leaky(LN(h)) in place
  k_ln_leaky<<<16384, t256, 0, stream>>>(h_b, lmg, lmb, h_b);
  // logits = h2 @ w2 + b2, split-K x2 -> planes logits / logits2 (2 blocks/CU)
  k_gemm_w2sk<<<dim3(2, 128, 2), t256, 0, stream>>>(h_b, w2T, b2, logits, logits2);
  k_final<<<4096, t256, 0, stream>>>(logits, logits2, e_b, l2g, l2b, out);
}